// Round 12
// baseline (101.295 us; speedup 1.0000x reference)
//
#include <hip/hip_runtime.h>
#include <hip/hip_bf16.h>
#include <math.h>

// Problem sizes (fixed by the reference)
#define NB   2
#define CC   256
#define PQ   4096   // 64*64 queries per image
#define PKV  1024   // 32*32 kv per image

#define NF (-INFINITY)
#define M0 24.0f    // fixed softmax offset (baked into EX; |e| << 80)
#define EXSTRIDE 36
#define EYSTRIDE 20

typedef __attribute__((ext_vector_type(8))) short short8;
typedef __attribute__((ext_vector_type(4))) float f32x4;

// ---------------------------------------------------------------------------
// Weights fp32 -> bf16, same [o][c] row-major layout (MFMA A-frag reads rows)
// ---------------------------------------------------------------------------
__global__ __launch_bounds__(256) void wconv4_kernel(
    const float* __restrict__ a, const float* __restrict__ b,
    const float* __restrict__ c, const float* __restrict__ d,
    __hip_bfloat16* __restrict__ ta, __hip_bfloat16* __restrict__ tb,
    __hip_bfloat16* __restrict__ tc, __hip_bfloat16* __restrict__ td) {
  const int which = blockIdx.y;
  const float* src = (which == 0) ? a : (which == 1) ? b : (which == 2) ? c : d;
  __hip_bfloat16* dst = (which == 0) ? ta : (which == 1) ? tb
                        : (which == 2) ? tc : td;
  const int i = blockIdx.x * 256 + threadIdx.x;   // 16384 float4 groups
  const float4 v = reinterpret_cast<const float4*>(src)[i];
  short4 s;
  s.x = __builtin_bit_cast(short, __float2bfloat16(v.x));
  s.y = __builtin_bit_cast(short, __float2bfloat16(v.y));
  s.z = __builtin_bit_cast(short, __float2bfloat16(v.z));
  s.w = __builtin_bit_cast(short, __float2bfloat16(v.w));
  reinterpret_cast<short4*>(dst)[i] = s;
}

// ---------------------------------------------------------------------------
// x fp32 [n][c][p] -> bf16 pixel-major xb[n][p][c]  (64x64 LDS tile)
// ---------------------------------------------------------------------------
__global__ __launch_bounds__(256) void xpose_kernel(
    const float* __restrict__ x, __hip_bfloat16* __restrict__ xb) {
  const int p0 = blockIdx.x * 64;
  const int c0 = blockIdx.y * 64;
  const int n = blockIdx.z;
  __shared__ float t[64][65];
  const int tid = threadIdx.x;
  {
    const int pl = tid & 63, cg = tid >> 6;
#pragma unroll
    for (int i = 0; i < 16; ++i) {
      const int cl = cg * 16 + i;
      t[cl][pl] = x[((size_t)n * 256 + c0 + cl) * PQ + p0 + pl];
    }
  }
  __syncthreads();
  const int cl = tid & 63;
#pragma unroll
  for (int j = 0; j < 16; ++j) {
    const int pl = (tid >> 6) + 4 * j;
    ((__hip_bfloat16*)xb)[((size_t)n * PQ + p0 + pl) * 256 + c0 + cl] =
        __float2bfloat16(t[cl][pl]);
  }
}

// ---------------------------------------------------------------------------
// Positional feature tables (bf16), deduplicated over diff d = i - 2k
// ---------------------------------------------------------------------------
__global__ __launch_bounds__(256) void posfeat_kernel(
    const float* __restrict__ fcx, const float* __restrict__ fcy,
    __hip_bfloat16* __restrict__ pembx_b, __hip_bfloat16* __restrict__ pemby_b) {
  const int dd = blockIdx.x;          // 0..125 -> diff = dd - 62
  const int which = blockIdx.y;
  const float* FC = which ? fcy : fcx;
  __hip_bfloat16* OUT = which ? pemby_b : pembx_b;
  __shared__ __align__(16) float feat[128];
  const int tid = threadIdx.x;
  if (tid < 64) {
    const float diff = (float)(dd - 62);
    const float dm = powf(1000.f, (float)tid * (1.f / 64.f));
    const float aa = diff / dm;
    feat[tid] = sinf(aa);
    feat[tid + 64] = cosf(aa);
  }
  __syncthreads();
  const float4* row4 = reinterpret_cast<const float4*>(FC + tid * 128);
  const float4* f4 = reinterpret_cast<const float4*>(feat);
  float s0 = 0.f, s1 = 0.f, s2 = 0.f, s3 = 0.f;
#pragma unroll
  for (int f = 0; f < 32; ++f) {
    const float4 fv = f4[f];
    const float4 rv = row4[f];
    s0 = fmaf(fv.x, rv.x, s0);
    s1 = fmaf(fv.y, rv.y, s1);
    s2 = fmaf(fv.z, rv.z, s2);
    s3 = fmaf(fv.w, rv.w, s3);
  }
  const float s = ((s0 + s1) + (s2 + s3)) * 0.70710678118654752440f;
  OUT[(size_t)dd * 256 + tid] = __float2bfloat16(s);
}

// ---------------------------------------------------------------------------
// MFMA GEMM: Q projection (R11-proven, unchanged).
// ---------------------------------------------------------------------------
__global__ __launch_bounds__(256) void gemm_q_kernel(
    const __hip_bfloat16* __restrict__ xb,
    const __hip_bfloat16* __restrict__ qw, const float* __restrict__ ab,
    const float* __restrict__ gb, __hip_bfloat16* __restrict__ qab,
    __hip_bfloat16* __restrict__ qgb) {
  const int p0 = blockIdx.x * 64;
  const int o0 = blockIdx.y * 64;
  const int n = blockIdx.z;
  const int tid = threadIdx.x;
  const int wv = tid >> 6, l = tid & 63, lc = l & 15, lq = l >> 4;
  const short* ar =
      (const short*)qw + ((size_t)(o0 + wv * 16 + lc)) * 256 + 8 * lq;
  const short* bbase = (const short*)xb + ((size_t)n * PQ + p0) * 256 + 8 * lq;
  const short* b0p = bbase + (size_t)(0 + lc) * 256;
  const short* b1p = bbase + (size_t)(16 + lc) * 256;
  const short* b2p = bbase + (size_t)(32 + lc) * 256;
  const short* b3p = bbase + (size_t)(48 + lc) * 256;
  f32x4 acc0 = {0.f, 0.f, 0.f, 0.f};
  f32x4 acc1 = {0.f, 0.f, 0.f, 0.f};
  f32x4 acc2 = {0.f, 0.f, 0.f, 0.f};
  f32x4 acc3 = {0.f, 0.f, 0.f, 0.f};
#pragma unroll
  for (int kt = 0; kt < 8; ++kt) {
    const short8 af = *reinterpret_cast<const short8*>(ar + kt * 32);
    acc0 = __builtin_amdgcn_mfma_f32_16x16x32_bf16(
        af, *reinterpret_cast<const short8*>(b0p + kt * 32), acc0, 0, 0, 0);
    acc1 = __builtin_amdgcn_mfma_f32_16x16x32_bf16(
        af, *reinterpret_cast<const short8*>(b1p + kt * 32), acc1, 0, 0, 0);
    acc2 = __builtin_amdgcn_mfma_f32_16x16x32_bf16(
        af, *reinterpret_cast<const short8*>(b2p + kt * 32), acc2, 0, 0, 0);
    acc3 = __builtin_amdgcn_mfma_f32_16x16x32_bf16(
        af, *reinterpret_cast<const short8*>(b3p + kt * 32), acc3, 0, 0, 0);
  }
#pragma unroll
  for (int r = 0; r < 4; ++r) {
    const int o = o0 + wv * 16 + 4 * lq + r;   // C row = 4*lq + r
    const float abo = ab[o], gbo = gb[o];
    const int head = o >> 5, dd = o & 31;
    const size_t gbase = (size_t)(n * 8 + head) * PQ;
    const float a_[4] = {acc0[r], acc1[r], acc2[r], acc3[r]};
#pragma unroll
    for (int nf = 0; nf < 4; ++nf) {
      const int p = p0 + 16 * nf + lc;
      const size_t idx = (gbase + p) * 32 + dd;
      qab[idx] = __float2bfloat16(a_[nf] + abo);
      qgb[idx] = __float2bfloat16(a_[nf] + gbo);
    }
  }
}

// ---------------------------------------------------------------------------
// MFMA GEMM: K/V projection (R11-proven, unchanged).
// ---------------------------------------------------------------------------
__global__ __launch_bounds__(256) void gemm_kv_kernel(
    const __hip_bfloat16* __restrict__ xb,
    const __hip_bfloat16* __restrict__ kw, const __hip_bfloat16* __restrict__ vw,
    __hip_bfloat16* __restrict__ k_lb, __hip_bfloat16* __restrict__ v_t) {
  const int p0 = blockIdx.x * 64;
  const int o0 = blockIdx.y * 64;
  const int n = blockIdx.z & 1;
  const bool isV = (blockIdx.z >> 1) != 0;
  const __hip_bfloat16* W = isV ? vw : kw;
  const int tid = threadIdx.x;
  const int wv = tid >> 6, l = tid & 63, lc = l & 15, lq = l >> 4;
  const short* ar =
      (const short*)W + ((size_t)(o0 + wv * 16 + lc)) * 256 + 8 * lq;
  const short* bb = (const short*)xb + (size_t)n * PQ * 256 + 8 * lq;
  const int pk0 = p0 + 0 + lc, pk1 = p0 + 16 + lc;
  const int pk2 = p0 + 32 + lc, pk3 = p0 + 48 + lc;
  const short* b0p = bb + (size_t)((pk0 >> 5) * 128 + (pk0 & 31) * 2) * 256;
  const short* b1p = bb + (size_t)((pk1 >> 5) * 128 + (pk1 & 31) * 2) * 256;
  const short* b2p = bb + (size_t)((pk2 >> 5) * 128 + (pk2 & 31) * 2) * 256;
  const short* b3p = bb + (size_t)((pk3 >> 5) * 128 + (pk3 & 31) * 2) * 256;
  f32x4 acc0 = {0.f, 0.f, 0.f, 0.f};
  f32x4 acc1 = {0.f, 0.f, 0.f, 0.f};
  f32x4 acc2 = {0.f, 0.f, 0.f, 0.f};
  f32x4 acc3 = {0.f, 0.f, 0.f, 0.f};
#pragma unroll
  for (int kt = 0; kt < 8; ++kt) {
    const short8 af = *reinterpret_cast<const short8*>(ar + kt * 32);
    acc0 = __builtin_amdgcn_mfma_f32_16x16x32_bf16(
        af, *reinterpret_cast<const short8*>(b0p + kt * 32), acc0, 0, 0, 0);
    acc1 = __builtin_amdgcn_mfma_f32_16x16x32_bf16(
        af, *reinterpret_cast<const short8*>(b1p + kt * 32), acc1, 0, 0, 0);
    acc2 = __builtin_amdgcn_mfma_f32_16x16x32_bf16(
        af, *reinterpret_cast<const short8*>(b2p + kt * 32), acc2, 0, 0, 0);
    acc3 = __builtin_amdgcn_mfma_f32_16x16x32_bf16(
        af, *reinterpret_cast<const short8*>(b3p + kt * 32), acc3, 0, 0, 0);
  }
#pragma unroll
  for (int r = 0; r < 4; ++r) {
    const int o = o0 + wv * 16 + 4 * lq + r;
    const int head = o >> 5, dd = o & 31;
    const float a_[4] = {acc0[r], acc1[r], acc2[r], acc3[r]};
#pragma unroll
    for (int nf = 0; nf < 4; ++nf) {
      const int p = p0 + 16 * nf + lc;
      if (!isV) {
        k_lb[((size_t)(n * 8 + head) * PKV + p) * 32 + dd] =
            __float2bfloat16(a_[nf]);
      } else {
        v_t[((size_t)(n * 8 + head) * 32 + dd) * PKV + p] =
            __float2bfloat16(a_[nf]);
      }
    }
  }
}

// ---------------------------------------------------------------------------
// Positional energy tables via MFMA (R11-proven, unchanged).
// ---------------------------------------------------------------------------
template <int MODE>
__global__ __launch_bounds__(256) void exy_kernel(
    const __hip_bfloat16* __restrict__ qgb_b,
    const __hip_bfloat16* __restrict__ pemb_b, float* __restrict__ OUT) {
  const int i = blockIdx.x;       // x (MODE0) or y (MODE1)
  const int g = blockIdx.y;
  const int head = g & 7;
  const int wv = threadIdx.x >> 6;
  const int l = threadIdx.x & 63;
  const int lc = l & 15, lq = l >> 4;

  const int rowi = wv * 16 + lc;  // y (MODE0) or x (MODE1)
  const int p = (MODE == 0) ? rowi * 64 + i : i * 64 + rowi;
  const short8 a = *reinterpret_cast<const short8*>(
      (const short*)qgb_b + ((size_t)g * PQ + p) * 32 + 8 * lq);

  int drow0, drow1;
  if (MODE == 0) {
    drow0 = i - 2 * lc + 62;
    drow1 = i - 2 * (lc + 16) + 62;
  } else {
    const int lo_y = max((i - 16) >> 1, 0);
    drow0 = i - 2 * (lo_y + lc) + 62;
    drow1 = i - 2 * (lo_y + lc + 16) + 62;
  }
  const short8 b0 = *reinterpret_cast<const short8*>(
      (const short*)pemb_b + (size_t)drow0 * 256 + head * 32 + 8 * lq);
  const short8 b1 = *reinterpret_cast<const short8*>(
      (const short*)pemb_b + (size_t)drow1 * 256 + head * 32 + 8 * lq);

  const f32x4 zero = {0.f, 0.f, 0.f, 0.f};
  const f32x4 c0 = __builtin_amdgcn_mfma_f32_16x16x32_bf16(a, b0, zero, 0, 0, 0);
  const f32x4 c1 = __builtin_amdgcn_mfma_f32_16x16x32_bf16(a, b1, zero, 0, 0, 0);

#pragma unroll
  for (int r = 0; r < 4; ++r) {
    const int rowr = wv * 16 + 4 * lq + r;
    const int pr = (MODE == 0) ? rowr * 64 + i : i * 64 + rowr;
    if (MODE == 0) {
      const int lox = max((i - 16) >> 1, 0);
      const int hix = min(((i + 17) >> 1) + 1, 32);
      float* o = OUT + ((size_t)g * PQ + pr) * EXSTRIDE;
      o[lc] = (lc >= lox && lc < hix) ? (c0[r] - M0) : -1e30f;
      o[16 + lc] = (lc + 16 >= lox && lc + 16 < hix) ? (c1[r] - M0) : -1e30f;
      if (lc < 4) o[32 + lc] = -1e30f;
    } else {
      float* o = OUT + ((size_t)g * PQ + pr) * EYSTRIDE;
      o[lc] = c0[r];
      if (lc < 4) o[16 + lc] = c1[r];
    }
  }
}

// ---------------------------------------------------------------------------
// MFMA local-window attention, 8-wave ky-parity split.
// Wave w: y-row = w&3, ky parity s = w>>2 (t = s, s+2, ...). No-max softmax
// makes the pair-merge a pure add (acc, lp) via LDS. Waves 0-3 normalize and
// store fp32 att (R10-proven epilogue; bf16 direct store is the known-bad path).
// ---------------------------------------------------------------------------
__global__ __launch_bounds__(512, 8) void attn_mfma_kernel(
    const __hip_bfloat16* __restrict__ qab_b,
    const __hip_bfloat16* __restrict__ k_lb,
    const __hip_bfloat16* __restrict__ v_t, const float* __restrict__ EX,
    const float* __restrict__ EY, float* __restrict__ att) {
  const int g = blockIdx.y;    // n*8 + head
  const int bx = blockIdx.x & 3;   // x-tile of 16
  const int by = blockIdx.x >> 2;  // y-tile of 4 rows
  const int tx = bx * 16;
  const int wv = threadIdx.x >> 6;   // 0..7
  const int yw = wv & 3;             // y-row within tile
  const int s = wv >> 2;             // ky parity
  const int y = by * 4 + yw;
  const int l = threadIdx.x & 63;
  const int lc = l & 15;   // col lane (q for S^T / vd for O)
  const int lq = l >> 4;   // quarter

  __shared__ float eybuf[4][EYSTRIDE][16];  // [yrow][t][q]
  __shared__ float mrg[4][64][9];           // [yrow][lane][acc0*4,acc1*4,lp]

  const int KLO = max((tx - 16) >> 1, 0);
  const int lo_y = max((y - 16) >> 1, 0);
  const int hi_y = min(((y + 17) >> 1) + 1, 32);
  const int NKY = hi_y - lo_y;

  const int xq = tx + lc;
  const int pq_ = y * 64 + xq;

  // Qa B-frag: lane holds Qa[d=8lq+j][q=lc]
  const short8 qa = *reinterpret_cast<const short8*>(
      (const short*)qab_b + ((size_t)g * PQ + pq_) * 32 + 8 * lq);

  // per-lane loop-invariant ex registers (mask, M0, x-positional term baked)
  const float* exr = EX + ((size_t)g * PQ + pq_) * EXSTRIDE;
  float exC0[4], exC1[4];
#pragma unroll
  for (int r = 0; r < 4; ++r) {
    exC0[r] = exr[KLO + 4 * lq + r];
    exC1[r] = exr[min(KLO + 16 + 4 * lq + r, 35)];
  }

  // ey -> LDS ([t][q] layout); written once per y-row by waves 0-3
  if (wv < 4) {
    const float* eyr = EY + ((size_t)g * PQ + pq_) * EYSTRIDE;
    const float4 e4 = *reinterpret_cast<const float4*>(eyr + 4 * lq);
#pragma unroll
    for (int j = 0; j < 4; ++j) eybuf[yw][4 * lq + j][lc] = e4[j];
    if (lq == 0) {
      const float4 e4b = *reinterpret_cast<const float4*>(eyr + 16);
#pragma unroll
      for (int j = 0; j < 4; ++j) eybuf[yw][16 + j][lc] = e4b[j];
    }
  }
  __syncthreads();

  const __hip_bfloat16* kb =
      k_lb + ((size_t)g * PKV + (size_t)lo_y * 32) * 32;
  const __hip_bfloat16* kb0 = kb + (KLO + lc) * 32 + 8 * lq;
  const __hip_bfloat16* kb1 = kb + min(KLO + 16 + lc, 31) * 32 + 8 * lq;
  const __hip_bfloat16* vb0 =
      v_t + ((size_t)g * 32 + lc) * PKV + (size_t)lo_y * 32 + KLO + 8 * lq;
  const __hip_bfloat16* vb1 = vb0 + 16 * PKV;

  f32x4 acc0 = {0.f, 0.f, 0.f, 0.f};
  f32x4 acc1 = {0.f, 0.f, 0.f, 0.f};
  float lp = 0.f;
  const int srcA = lc + ((l & 16) << 1);  // lane lc + 32*(lq&1)
  const int srcB = srcA + 16;
  const bool hiL = (l & 32) != 0;

#pragma unroll 1
  for (int t = s; t < NKY; t += 2) {
    const short8 k0 = *reinterpret_cast<const short8*>(kb0 + t * 1024);
    const short8 k1 = *reinterpret_cast<const short8*>(kb1 + t * 1024);
    const short8 v0 = *reinterpret_cast<const short8*>(vb0 + t * 32);
    const short8 v1 = *reinterpret_cast<const short8*>(vb1 + t * 32);
    const f32x4 zero = {0.f, 0.f, 0.f, 0.f};
    // S^T tiles: rows kx_local = 4*lq + r, cols q = lc
    const f32x4 s0 = __builtin_amdgcn_mfma_f32_16x16x32_bf16(k0, qa, zero, 0, 0, 0);
    const f32x4 s1 = __builtin_amdgcn_mfma_f32_16x16x32_bf16(k1, qa, zero, 0, 0, 0);
    const float eyC = eybuf[yw][t][lc];
    float p0[4], p1[4];
#pragma unroll
    for (int r = 0; r < 4; ++r) {
      p0[r] = __expf(s0[r] + exC0[r] + eyC);   // masked: exC=-1e30 -> 0
      p1[r] = __expf(s1[r] + exC1[r] + eyC);
    }
    lp += ((p0[0] + p0[1]) + (p0[2] + p0[3])) +
          ((p1[0] + p1[1]) + (p1[2] + p1[3]));
    int w00, w01, w10, w11;
    asm("v_cvt_pk_bf16_f32 %0, %1, %2" : "=v"(w00) : "v"(p0[0]), "v"(p0[1]));
    asm("v_cvt_pk_bf16_f32 %0, %1, %2" : "=v"(w01) : "v"(p0[2]), "v"(p0[3]));
    asm("v_cvt_pk_bf16_f32 %0, %1, %2" : "=v"(w10) : "v"(p1[0]), "v"(p1[1]));
    asm("v_cvt_pk_bf16_f32 %0, %1, %2" : "=v"(w11) : "v"(p1[2]), "v"(p1[3]));
    const int a0 = __shfl(w00, srcA, 64), b0 = __shfl(w10, srcA, 64);
    const int a1 = __shfl(w01, srcA, 64), b1 = __shfl(w11, srcA, 64);
    const int a2 = __shfl(w00, srcB, 64), b2 = __shfl(w10, srcB, 64);
    const int a3 = __shfl(w01, srcB, 64), b3 = __shfl(w11, srcB, 64);
    int4 pw;
    pw.x = hiL ? b0 : a0;
    pw.y = hiL ? b1 : a1;
    pw.z = hiL ? b2 : a2;
    pw.w = hiL ? b3 : a3;
    const short8 pf = __builtin_bit_cast(short8, pw);
    acc0 = __builtin_amdgcn_mfma_f32_16x16x32_bf16(pf, v0, acc0, 0, 0, 0);
    acc1 = __builtin_amdgcn_mfma_f32_16x16x32_bf16(pf, v1, acc1, 0, 0, 0);
  }

  // pair-merge: parity-1 waves deposit (acc, lp); parity-0 waves add.
  if (s == 1) {
    float* m = mrg[yw][l];
#pragma unroll
    for (int r = 0; r < 4; ++r) m[r] = acc0[r];
#pragma unroll
    for (int r = 0; r < 4; ++r) m[4 + r] = acc1[r];
    m[8] = lp;
  }
  __syncthreads();
  if (s == 1) return;
  {
    const float* m = mrg[yw][l];
#pragma unroll
    for (int r = 0; r < 4; ++r) acc0[r] += m[r];
#pragma unroll
    for (int r = 0; r < 4; ++r) acc1[r] += m[4 + r];
    lp += m[8];
  }

  // l: sum over the 4 lq groups -> every lane holds L[q=lc]
  lp += __shfl_xor(lp, 16);
  lp += __shfl_xor(lp, 32);
  const float invall = 1.f / lp;
#pragma unroll
  for (int r = 0; r < 4; ++r) {
    const float inv = __shfl(invall, 4 * lq + r, 16);  // L for q = 4lq+r
    const int p = y * 64 + tx + 4 * lq + r;
    att[((size_t)g * 32 + lc) * PQ + p] = acc0[r] * inv;
    att[((size_t)g * 32 + 16 + lc) * PQ + p] = acc1[r] * inv;
  }
}

// ---------------------------------------------------------------------------
// att fp32 [g*32+vd][p] -> attb bf16 [n][p][c]  (R11-proven, unchanged)
// ---------------------------------------------------------------------------
__global__ __launch_bounds__(256) void att2b_kernel(
    const float* __restrict__ att, __hip_bfloat16* __restrict__ attb) {
  const int g = blockIdx.y;
  const int nImg = g >> 3, hd = g & 7;
  const int p0 = blockIdx.x * 64;
  const int tid = threadIdx.x;
  __shared__ float t[32][65];
  {
    const int pl = tid & 63;
    const int v0 = (tid >> 6) * 8;
#pragma unroll
    for (int j = 0; j < 8; ++j)
      t[v0 + j][pl] = att[((size_t)g * 32 + v0 + j) * PQ + p0 + pl];
  }
  __syncthreads();
  const int pl = tid & 63;
  const int vq = tid >> 6;
  short8 s;
#pragma unroll
  for (int j = 0; j < 8; ++j)
    s[j] = __builtin_bit_cast(short, __float2bfloat16(t[vq * 8 + j][pl]));
  *reinterpret_cast<short8*>(
      (short*)attb + ((size_t)nImg * PQ + p0 + pl) * 256 + hd * 32 + vq * 8) = s;
}

// ---------------------------------------------------------------------------
// MFMA GEMM: output projection + bias + gamma + residual (R11-proven).
// ---------------------------------------------------------------------------
__global__ __launch_bounds__(256) void gemm_out_kernel(
    const __hip_bfloat16* __restrict__ attb,
    const __hip_bfloat16* __restrict__ pw, const float* __restrict__ pb,
    const float* __restrict__ gamma, const float* __restrict__ x_in,
    float* __restrict__ out) {
  const int p0 = blockIdx.x * 64;
  const int o0 = blockIdx.y * 64;
  const int n = blockIdx.z;
  const int tid = threadIdx.x;
  const int wv = tid >> 6, l = tid & 63, lc = l & 15, lq = l >> 4;
  const short* ar =
      (const short*)pw + ((size_t)(o0 + wv * 16 + lc)) * 256 + 8 * lq;
  const short* bbase = (const short*)attb + ((size_t)n * PQ + p0) * 256 + 8 * lq;
  const short* b0p = bbase + (size_t)(0 + lc) * 256;
  const short* b1p = bbase + (size_t)(16 + lc) * 256;
  const short* b2p = bbase + (size_t)(32 + lc) * 256;
  const short* b3p = bbase + (size_t)(48 + lc) * 256;
  f32x4 acc0 = {0.f, 0.f, 0.f, 0.f};
  f32x4 acc1 = {0.f, 0.f, 0.f, 0.f};
  f32x4 acc2 = {0.f, 0.f, 0.f, 0.f};
  f32x4 acc3 = {0.f, 0.f, 0.f, 0.f};
#pragma unroll
  for (int kt = 0; kt < 8; ++kt) {
    const short8 af = *reinterpret_cast<const short8*>(ar + kt * 32);
    acc0 = __builtin_amdgcn_mfma_f32_16x16x32_bf16(
        af, *reinterpret_cast<const short8*>(b0p + kt * 32), acc0, 0, 0, 0);
    acc1 = __builtin_amdgcn_mfma_f32_16x16x32_bf16(
        af, *reinterpret_cast<const short8*>(b1p + kt * 32), acc1, 0, 0, 0);
    acc2 = __builtin_amdgcn_mfma_f32_16x16x32_bf16(
        af, *reinterpret_cast<const short8*>(b2p + kt * 32), acc2, 0, 0, 0);
    acc3 = __builtin_amdgcn_mfma_f32_16x16x32_bf16(
        af, *reinterpret_cast<const short8*>(b3p + kt * 32), acc3, 0, 0, 0);
  }
  const float gm = gamma[0];
#pragma unroll
  for (int r = 0; r < 4; ++r) {
    const int o = o0 + wv * 16 + 4 * lq + r;   // C row = 4*lq + r
    const float bo = pb[o];
    const size_t obase = ((size_t)n * 256 + o) * PQ;
    const size_t i0 = obase + (p0 + 0 + lc);
    const size_t i1 = obase + (p0 + 16 + lc);
    const size_t i2 = obase + (p0 + 32 + lc);
    const size_t i3 = obase + (p0 + 48 + lc);
    out[i0] = fmaf(gm, acc0[r] + bo, x_in[i0]);
    out[i1] = fmaf(gm, acc1[r] + bo, x_in[i1]);
    out[i2] = fmaf(gm, acc2[r] + bo, x_in[i2]);
    out[i3] = fmaf(gm, acc3[r] + bo, x_in[i3]);
  }
}

// ---------------------------------------------------------------------------
extern "C" void kernel_launch(void* const* d_in, const int* in_sizes, int n_in,
                              void* d_out, int out_size, void* d_ws,
                              size_t ws_size, hipStream_t stream) {
  const float* x = (const float*)d_in[0];
  const float* q_w = (const float*)d_in[1];
  const float* k_w = (const float*)d_in[2];
  const float* v_w = (const float*)d_in[3];
  const float* fcx_w = (const float*)d_in[4];
  const float* fcy_w = (const float*)d_in[5];
  const float* ab = (const float*)d_in[6];
  const float* gb = (const float*)d_in[7];
  const float* proj_w = (const float*)d_in[8];
  const float* proj_b = (const float*)d_in[9];
  const float* gamma = (const float*)d_in[10];
  float* out = (float*)d_out;

  float* ws = (float*)d_ws;
  float* att = ws;                       // 2,097,152 f
  float* EX = att + 2097152;             // 2,359,296 f
  float* EY = EX + 2359296;              // 1,310,720 f
  __hip_bfloat16* bp = (__hip_bfloat16*)(EY + 1310720);
  __hip_bfloat16* qab_b = bp;   bp += 2097152;
  __hip_bfloat16* qgb_b = bp;   bp += 2097152;
  __hip_bfloat16* k_lb = bp;    bp += 524288;
  __hip_bfloat16* v_t = bp;     bp += 524288;
  __hip_bfloat16* pembx_b = bp; bp += 32256;
  __hip_bfloat16* pemby_b = bp; bp += 32256;
  __hip_bfloat16* qw_b = bp;    bp += 65536;
  __hip_bfloat16* kw_b = bp;    bp += 65536;
  __hip_bfloat16* vw_b = bp;    bp += 65536;
  __hip_bfloat16* pw_b = bp;    bp += 65536;
  __hip_bfloat16* xb = bp;      bp += 2097152;
  __hip_bfloat16* attb = bp;    bp += 2097152;
  // total = 42.6 MB (R11-proven layout, unchanged)

  wconv4_kernel<<<dim3(64, 4), 256, 0, stream>>>(q_w, k_w, v_w, proj_w, qw_b,
                                                 kw_b, vw_b, pw_b);
  posfeat_kernel<<<dim3(126, 2), 256, 0, stream>>>(fcx_w, fcy_w, pembx_b,
                                                   pemby_b);
  xpose_kernel<<<dim3(64, 4, 2), 256, 0, stream>>>(x, xb);
  gemm_q_kernel<<<dim3(64, 4, 2), 256, 0, stream>>>(xb, qw_b, ab, gb, qab_b,
                                                    qgb_b);
  gemm_kv_kernel<<<dim3(16, 4, 4), 256, 0, stream>>>(xb, kw_b, vw_b, k_lb,
                                                     v_t);
  exy_kernel<0><<<dim3(64, 16), 256, 0, stream>>>(qgb_b, pembx_b, EX);
  exy_kernel<1><<<dim3(64, 16), 256, 0, stream>>>(qgb_b, pemby_b, EY);
  attn_mfma_kernel<<<dim3(64, 16), 512, 0, stream>>>(qab_b, k_lb, v_t, EX, EY,
                                                     att);
  att2b_kernel<<<dim3(64, 16), 256, 0, stream>>>(att, attb);
  gemm_out_kernel<<<dim3(64, 4, 2), 256, 0, stream>>>(attb, pw_b, proj_b,
                                                      gamma, x, out);
}

// Round 13
// 95.830 us; speedup vs baseline: 1.0570x; 1.0570x over previous
//
#include <hip/hip_runtime.h>
#include <hip/hip_bf16.h>
#include <math.h>

// Problem sizes (fixed by the reference)
#define NB   2
#define CC   256
#define PQ   4096   // 64*64 queries per image
#define PKV  1024   // 32*32 kv per image

#define NF (-INFINITY)
#define M0 24.0f    // fixed softmax offset (baked into EX; |e| << 80)
#define EXSTRIDE 36
#define EYSTRIDE 20

typedef __attribute__((ext_vector_type(8))) short short8;
typedef __attribute__((ext_vector_type(4))) float f32x4;

// ---------------------------------------------------------------------------
// Fused prep: blocks 0..255 = weights fp32->bf16 ([o][c] layout);
// blocks 256..507 = posfeat pemb tables (dd = (bid-256)>>1, mode = bid&1).
// ---------------------------------------------------------------------------
__global__ __launch_bounds__(256) void prep_kernel(
    const float* __restrict__ q_w, const float* __restrict__ k_w,
    const float* __restrict__ v_w, const float* __restrict__ proj_w,
    __hip_bfloat16* __restrict__ qw_b, __hip_bfloat16* __restrict__ kw_b,
    __hip_bfloat16* __restrict__ vw_b, __hip_bfloat16* __restrict__ pw_b,
    const float* __restrict__ fcx, const float* __restrict__ fcy,
    __hip_bfloat16* __restrict__ pembx_b,
    __hip_bfloat16* __restrict__ pemby_b) {
  __shared__ __align__(16) float feat[128];
  const int bid = blockIdx.x;
  const int tid = threadIdx.x;
  if (bid < 256) {
    const int which = bid >> 6;
    const float* src = (which == 0) ? q_w : (which == 1) ? k_w
                       : (which == 2) ? v_w : proj_w;
    __hip_bfloat16* dst = (which == 0) ? qw_b : (which == 1) ? kw_b
                          : (which == 2) ? vw_b : pw_b;
    const int i = (bid & 63) * 256 + tid;
    const float4 v = reinterpret_cast<const float4*>(src)[i];
    short4 s;
    s.x = __builtin_bit_cast(short, __float2bfloat16(v.x));
    s.y = __builtin_bit_cast(short, __float2bfloat16(v.y));
    s.z = __builtin_bit_cast(short, __float2bfloat16(v.z));
    s.w = __builtin_bit_cast(short, __float2bfloat16(v.w));
    reinterpret_cast<short4*>(dst)[i] = s;
  } else {
    const int pb = bid - 256;        // 0..251
    const int dd = pb >> 1;          // 0..125 -> diff = dd - 62
    const int which = pb & 1;
    const float* FC = which ? fcy : fcx;
    __hip_bfloat16* OUT = which ? pemby_b : pembx_b;
    if (tid < 64) {
      const float diff = (float)(dd - 62);
      const float dm = powf(1000.f, (float)tid * (1.f / 64.f));
      const float aa = diff / dm;
      feat[tid] = sinf(aa);
      feat[tid + 64] = cosf(aa);
    }
    __syncthreads();
    const float4* row4 = reinterpret_cast<const float4*>(FC + tid * 128);
    const float4* f4 = reinterpret_cast<const float4*>(feat);
    float s0 = 0.f, s1 = 0.f, s2 = 0.f, s3 = 0.f;
#pragma unroll
    for (int f = 0; f < 32; ++f) {
      const float4 fv = f4[f];
      const float4 rv = row4[f];
      s0 = fmaf(fv.x, rv.x, s0);
      s1 = fmaf(fv.y, rv.y, s1);
      s2 = fmaf(fv.z, rv.z, s2);
      s3 = fmaf(fv.w, rv.w, s3);
    }
    const float s = ((s0 + s1) + (s2 + s3)) * 0.70710678118654752440f;
    OUT[(size_t)dd * 256 + tid] = __float2bfloat16(s);
  }
}

// ---------------------------------------------------------------------------
// x fp32 [n][c][p] -> bf16 pixel-major xb[n][p][c]  (R12-proven, unchanged)
// ---------------------------------------------------------------------------
__global__ __launch_bounds__(256) void xpose_kernel(
    const float* __restrict__ x, __hip_bfloat16* __restrict__ xb) {
  const int p0 = blockIdx.x * 64;
  const int c0 = blockIdx.y * 64;
  const int n = blockIdx.z;
  __shared__ float t[64][65];
  const int tid = threadIdx.x;
  {
    const int pl = tid & 63, cg = tid >> 6;
#pragma unroll
    for (int i = 0; i < 16; ++i) {
      const int cl = cg * 16 + i;
      t[cl][pl] = x[((size_t)n * 256 + c0 + cl) * PQ + p0 + pl];
    }
  }
  __syncthreads();
  const int cl = tid & 63;
#pragma unroll
  for (int j = 0; j < 16; ++j) {
    const int pl = (tid >> 6) + 4 * j;
    ((__hip_bfloat16*)xb)[((size_t)n * PQ + p0 + pl) * 256 + c0 + cl] =
        __float2bfloat16(t[cl][pl]);
  }
}

// ---------------------------------------------------------------------------
// Fused Q + K/V projection GEMMs, 32-wide p-tiles for occupancy.
// blocks 0..1023: Q path  (n=bid&1, o-tile=(bid>>1)&3, p-tile=bid>>3)
// blocks 1024..1535: KV   (kb=bid-1024: n=kb&1, o=(kb>>1)&3, isV=(kb>>3)&1,
//                          p-tile=kb>>4)
// Math identical to R12's gemm_q/gemm_kv (truncated to 2 B-frags).
// ---------------------------------------------------------------------------
__global__ __launch_bounds__(256) void gemm_qkv_kernel(
    const __hip_bfloat16* __restrict__ xb,
    const __hip_bfloat16* __restrict__ qw, const __hip_bfloat16* __restrict__ kw,
    const __hip_bfloat16* __restrict__ vw, const float* __restrict__ ab,
    const float* __restrict__ gb, __hip_bfloat16* __restrict__ qab,
    __hip_bfloat16* __restrict__ qgb, __hip_bfloat16* __restrict__ k_lb,
    __hip_bfloat16* __restrict__ v_t) {
  const int bid = blockIdx.x;
  const int tid = threadIdx.x;
  const int wv = tid >> 6, l = tid & 63, lc = l & 15, lq = l >> 4;
  if (bid < 1024) {
    const int n = bid & 1;
    const int o0 = ((bid >> 1) & 3) * 64;
    const int p0 = (bid >> 3) * 32;
    const short* ar =
        (const short*)qw + ((size_t)(o0 + wv * 16 + lc)) * 256 + 8 * lq;
    const short* bbase =
        (const short*)xb + ((size_t)n * PQ + p0) * 256 + 8 * lq;
    const short* b0p = bbase + (size_t)(0 + lc) * 256;
    const short* b1p = bbase + (size_t)(16 + lc) * 256;
    f32x4 acc0 = {0.f, 0.f, 0.f, 0.f};
    f32x4 acc1 = {0.f, 0.f, 0.f, 0.f};
#pragma unroll
    for (int kt = 0; kt < 8; ++kt) {
      const short8 af = *reinterpret_cast<const short8*>(ar + kt * 32);
      acc0 = __builtin_amdgcn_mfma_f32_16x16x32_bf16(
          af, *reinterpret_cast<const short8*>(b0p + kt * 32), acc0, 0, 0, 0);
      acc1 = __builtin_amdgcn_mfma_f32_16x16x32_bf16(
          af, *reinterpret_cast<const short8*>(b1p + kt * 32), acc1, 0, 0, 0);
    }
#pragma unroll
    for (int r = 0; r < 4; ++r) {
      const int o = o0 + wv * 16 + 4 * lq + r;
      const float abo = ab[o], gbo = gb[o];
      const int head = o >> 5, dd = o & 31;
      const size_t gbase = (size_t)(n * 8 + head) * PQ;
      const float a_[2] = {acc0[r], acc1[r]};
#pragma unroll
      for (int nf = 0; nf < 2; ++nf) {
        const int p = p0 + 16 * nf + lc;
        const size_t idx = (gbase + p) * 32 + dd;
        qab[idx] = __float2bfloat16(a_[nf] + abo);
        qgb[idx] = __float2bfloat16(a_[nf] + gbo);
      }
    }
  } else {
    const int kb2 = bid - 1024;
    const int n = kb2 & 1;
    const int o0 = ((kb2 >> 1) & 3) * 64;
    const bool isV = ((kb2 >> 3) & 1) != 0;
    const int p0 = (kb2 >> 4) * 32;
    const __hip_bfloat16* W = isV ? vw : kw;
    const short* ar =
        (const short*)W + ((size_t)(o0 + wv * 16 + lc)) * 256 + 8 * lq;
    const short* bb = (const short*)xb + (size_t)n * PQ * 256 + 8 * lq;
    const int pk0 = p0 + 0 + lc, pk1 = p0 + 16 + lc;
    const short* b0p = bb + (size_t)((pk0 >> 5) * 128 + (pk0 & 31) * 2) * 256;
    const short* b1p = bb + (size_t)((pk1 >> 5) * 128 + (pk1 & 31) * 2) * 256;
    f32x4 acc0 = {0.f, 0.f, 0.f, 0.f};
    f32x4 acc1 = {0.f, 0.f, 0.f, 0.f};
#pragma unroll
    for (int kt = 0; kt < 8; ++kt) {
      const short8 af = *reinterpret_cast<const short8*>(ar + kt * 32);
      acc0 = __builtin_amdgcn_mfma_f32_16x16x32_bf16(
          af, *reinterpret_cast<const short8*>(b0p + kt * 32), acc0, 0, 0, 0);
      acc1 = __builtin_amdgcn_mfma_f32_16x16x32_bf16(
          af, *reinterpret_cast<const short8*>(b1p + kt * 32), acc1, 0, 0, 0);
    }
#pragma unroll
    for (int r = 0; r < 4; ++r) {
      const int o = o0 + wv * 16 + 4 * lq + r;
      const int head = o >> 5, dd = o & 31;
      const float a_[2] = {acc0[r], acc1[r]};
#pragma unroll
      for (int nf = 0; nf < 2; ++nf) {
        const int p = p0 + 16 * nf + lc;
        if (!isV) {
          k_lb[((size_t)(n * 8 + head) * PKV + p) * 32 + dd] =
              __float2bfloat16(a_[nf]);
        } else {
          v_t[((size_t)(n * 8 + head) * 32 + dd) * PKV + p] =
              __float2bfloat16(a_[nf]);
        }
      }
    }
  }
}

// ---------------------------------------------------------------------------
// Positional energy tables via MFMA; fused modes (blockIdx.z: 0=EX, 1=EY).
// Body identical to R12's exy_kernel<MODE>.
// ---------------------------------------------------------------------------
__global__ __launch_bounds__(256) void exy_kernel(
    const __hip_bfloat16* __restrict__ qgb_b,
    const __hip_bfloat16* __restrict__ pembx_b,
    const __hip_bfloat16* __restrict__ pemby_b, float* __restrict__ EX,
    float* __restrict__ EY) {
  const int MODE = blockIdx.z;
  const int i = blockIdx.x;       // x (MODE0) or y (MODE1)
  const int g = blockIdx.y;
  const int head = g & 7;
  const __hip_bfloat16* pemb_b = MODE ? pemby_b : pembx_b;
  const int wv = threadIdx.x >> 6;
  const int l = threadIdx.x & 63;
  const int lc = l & 15, lq = l >> 4;

  const int rowi = wv * 16 + lc;  // y (MODE0) or x (MODE1)
  const int p = (MODE == 0) ? rowi * 64 + i : i * 64 + rowi;
  const short8 a = *reinterpret_cast<const short8*>(
      (const short*)qgb_b + ((size_t)g * PQ + p) * 32 + 8 * lq);

  int drow0, drow1;
  if (MODE == 0) {
    drow0 = i - 2 * lc + 62;
    drow1 = i - 2 * (lc + 16) + 62;
  } else {
    const int lo_y = max((i - 16) >> 1, 0);
    drow0 = i - 2 * (lo_y + lc) + 62;
    drow1 = i - 2 * (lo_y + lc + 16) + 62;
  }
  const short8 b0 = *reinterpret_cast<const short8*>(
      (const short*)pemb_b + (size_t)drow0 * 256 + head * 32 + 8 * lq);
  const short8 b1 = *reinterpret_cast<const short8*>(
      (const short*)pemb_b + (size_t)drow1 * 256 + head * 32 + 8 * lq);

  const f32x4 zero = {0.f, 0.f, 0.f, 0.f};
  const f32x4 c0 = __builtin_amdgcn_mfma_f32_16x16x32_bf16(a, b0, zero, 0, 0, 0);
  const f32x4 c1 = __builtin_amdgcn_mfma_f32_16x16x32_bf16(a, b1, zero, 0, 0, 0);

#pragma unroll
  for (int r = 0; r < 4; ++r) {
    const int rowr = wv * 16 + 4 * lq + r;
    const int pr = (MODE == 0) ? rowr * 64 + i : i * 64 + rowr;
    if (MODE == 0) {
      const int lox = max((i - 16) >> 1, 0);
      const int hix = min(((i + 17) >> 1) + 1, 32);
      float* o = EX + ((size_t)g * PQ + pr) * EXSTRIDE;
      o[lc] = (lc >= lox && lc < hix) ? (c0[r] - M0) : -1e30f;
      o[16 + lc] = (lc + 16 >= lox && lc + 16 < hix) ? (c1[r] - M0) : -1e30f;
      if (lc < 4) o[32 + lc] = -1e30f;
    } else {
      float* o = EY + ((size_t)g * PQ + pr) * EYSTRIDE;
      o[lc] = c0[r];
      if (lc < 4) o[16 + lc] = c1[r];
    }
  }
}

// ---------------------------------------------------------------------------
// MFMA local-window attention, 8-wave ky-parity split (R12-proven, unchanged).
// ---------------------------------------------------------------------------
__global__ __launch_bounds__(512, 8) void attn_mfma_kernel(
    const __hip_bfloat16* __restrict__ qab_b,
    const __hip_bfloat16* __restrict__ k_lb,
    const __hip_bfloat16* __restrict__ v_t, const float* __restrict__ EX,
    const float* __restrict__ EY, float* __restrict__ att) {
  const int g = blockIdx.y;    // n*8 + head
  const int bx = blockIdx.x & 3;   // x-tile of 16
  const int by = blockIdx.x >> 2;  // y-tile of 4 rows
  const int tx = bx * 16;
  const int wv = threadIdx.x >> 6;   // 0..7
  const int yw = wv & 3;             // y-row within tile
  const int s = wv >> 2;             // ky parity
  const int y = by * 4 + yw;
  const int l = threadIdx.x & 63;
  const int lc = l & 15;   // col lane (q for S^T / vd for O)
  const int lq = l >> 4;   // quarter

  __shared__ float eybuf[4][EYSTRIDE][16];  // [yrow][t][q]
  __shared__ float mrg[4][64][9];           // [yrow][lane][acc0*4,acc1*4,lp]

  const int KLO = max((tx - 16) >> 1, 0);
  const int lo_y = max((y - 16) >> 1, 0);
  const int hi_y = min(((y + 17) >> 1) + 1, 32);
  const int NKY = hi_y - lo_y;

  const int xq = tx + lc;
  const int pq_ = y * 64 + xq;

  // Qa B-frag: lane holds Qa[d=8lq+j][q=lc]
  const short8 qa = *reinterpret_cast<const short8*>(
      (const short*)qab_b + ((size_t)g * PQ + pq_) * 32 + 8 * lq);

  // per-lane loop-invariant ex registers (mask, M0, x-positional term baked)
  const float* exr = EX + ((size_t)g * PQ + pq_) * EXSTRIDE;
  float exC0[4], exC1[4];
#pragma unroll
  for (int r = 0; r < 4; ++r) {
    exC0[r] = exr[KLO + 4 * lq + r];
    exC1[r] = exr[min(KLO + 16 + 4 * lq + r, 35)];
  }

  // ey -> LDS ([t][q] layout); written once per y-row by waves 0-3
  if (wv < 4) {
    const float* eyr = EY + ((size_t)g * PQ + pq_) * EYSTRIDE;
    const float4 e4 = *reinterpret_cast<const float4*>(eyr + 4 * lq);
#pragma unroll
    for (int j = 0; j < 4; ++j) eybuf[yw][4 * lq + j][lc] = e4[j];
    if (lq == 0) {
      const float4 e4b = *reinterpret_cast<const float4*>(eyr + 16);
#pragma unroll
      for (int j = 0; j < 4; ++j) eybuf[yw][16 + j][lc] = e4b[j];
    }
  }
  __syncthreads();

  const __hip_bfloat16* kb =
      k_lb + ((size_t)g * PKV + (size_t)lo_y * 32) * 32;
  const __hip_bfloat16* kb0 = kb + (KLO + lc) * 32 + 8 * lq;
  const __hip_bfloat16* kb1 = kb + min(KLO + 16 + lc, 31) * 32 + 8 * lq;
  const __hip_bfloat16* vb0 =
      v_t + ((size_t)g * 32 + lc) * PKV + (size_t)lo_y * 32 + KLO + 8 * lq;
  const __hip_bfloat16* vb1 = vb0 + 16 * PKV;

  f32x4 acc0 = {0.f, 0.f, 0.f, 0.f};
  f32x4 acc1 = {0.f, 0.f, 0.f, 0.f};
  float lp = 0.f;
  const int srcA = lc + ((l & 16) << 1);  // lane lc + 32*(lq&1)
  const int srcB = srcA + 16;
  const bool hiL = (l & 32) != 0;

#pragma unroll 1
  for (int t = s; t < NKY; t += 2) {
    const short8 k0 = *reinterpret_cast<const short8*>(kb0 + t * 1024);
    const short8 k1 = *reinterpret_cast<const short8*>(kb1 + t * 1024);
    const short8 v0 = *reinterpret_cast<const short8*>(vb0 + t * 32);
    const short8 v1 = *reinterpret_cast<const short8*>(vb1 + t * 32);
    const f32x4 zero = {0.f, 0.f, 0.f, 0.f};
    // S^T tiles: rows kx_local = 4*lq + r, cols q = lc
    const f32x4 s0 = __builtin_amdgcn_mfma_f32_16x16x32_bf16(k0, qa, zero, 0, 0, 0);
    const f32x4 s1 = __builtin_amdgcn_mfma_f32_16x16x32_bf16(k1, qa, zero, 0, 0, 0);
    const float eyC = eybuf[yw][t][lc];
    float p0[4], p1[4];
#pragma unroll
    for (int r = 0; r < 4; ++r) {
      p0[r] = __expf(s0[r] + exC0[r] + eyC);   // masked: exC=-1e30 -> 0
      p1[r] = __expf(s1[r] + exC1[r] + eyC);
    }
    lp += ((p0[0] + p0[1]) + (p0[2] + p0[3])) +
          ((p1[0] + p1[1]) + (p1[2] + p1[3]));
    int w00, w01, w10, w11;
    asm("v_cvt_pk_bf16_f32 %0, %1, %2" : "=v"(w00) : "v"(p0[0]), "v"(p0[1]));
    asm("v_cvt_pk_bf16_f32 %0, %1, %2" : "=v"(w01) : "v"(p0[2]), "v"(p0[3]));
    asm("v_cvt_pk_bf16_f32 %0, %1, %2" : "=v"(w10) : "v"(p1[0]), "v"(p1[1]));
    asm("v_cvt_pk_bf16_f32 %0, %1, %2" : "=v"(w11) : "v"(p1[2]), "v"(p1[3]));
    const int a0 = __shfl(w00, srcA, 64), b0 = __shfl(w10, srcA, 64);
    const int a1 = __shfl(w01, srcA, 64), b1 = __shfl(w11, srcA, 64);
    const int a2 = __shfl(w00, srcB, 64), b2 = __shfl(w10, srcB, 64);
    const int a3 = __shfl(w01, srcB, 64), b3 = __shfl(w11, srcB, 64);
    int4 pw;
    pw.x = hiL ? b0 : a0;
    pw.y = hiL ? b1 : a1;
    pw.z = hiL ? b2 : a2;
    pw.w = hiL ? b3 : a3;
    const short8 pf = __builtin_bit_cast(short8, pw);
    acc0 = __builtin_amdgcn_mfma_f32_16x16x32_bf16(pf, v0, acc0, 0, 0, 0);
    acc1 = __builtin_amdgcn_mfma_f32_16x16x32_bf16(pf, v1, acc1, 0, 0, 0);
  }

  // pair-merge: parity-1 waves deposit (acc, lp); parity-0 waves add.
  if (s == 1) {
    float* m = mrg[yw][l];
#pragma unroll
    for (int r = 0; r < 4; ++r) m[r] = acc0[r];
#pragma unroll
    for (int r = 0; r < 4; ++r) m[4 + r] = acc1[r];
    m[8] = lp;
  }
  __syncthreads();
  if (s == 1) return;
  {
    const float* m = mrg[yw][l];
#pragma unroll
    for (int r = 0; r < 4; ++r) acc0[r] += m[r];
#pragma unroll
    for (int r = 0; r < 4; ++r) acc1[r] += m[4 + r];
    lp += m[8];
  }

  // l: sum over the 4 lq groups -> every lane holds L[q=lc]
  lp += __shfl_xor(lp, 16);
  lp += __shfl_xor(lp, 32);
  const float invall = 1.f / lp;
#pragma unroll
  for (int r = 0; r < 4; ++r) {
    const float inv = __shfl(invall, 4 * lq + r, 16);  // L for q = 4lq+r
    const int p = y * 64 + tx + 4 * lq + r;
    att[((size_t)g * 32 + lc) * PQ + p] = acc0[r] * inv;
    att[((size_t)g * 32 + 16 + lc) * PQ + p] = acc1[r] * inv;
  }
}

// ---------------------------------------------------------------------------
// att fp32 [g*32+vd][p] -> attb bf16 [n][p][c]  (R12-proven, unchanged)
// ---------------------------------------------------------------------------
__global__ __launch_bounds__(256) void att2b_kernel(
    const float* __restrict__ att, __hip_bfloat16* __restrict__ attb) {
  const int g = blockIdx.y;
  const int nImg = g >> 3, hd = g & 7;
  const int p0 = blockIdx.x * 64;
  const int tid = threadIdx.x;
  __shared__ float t[32][65];
  {
    const int pl = tid & 63;
    const int v0 = (tid >> 6) * 8;
#pragma unroll
    for (int j = 0; j < 8; ++j)
      t[v0 + j][pl] = att[((size_t)g * 32 + v0 + j) * PQ + p0 + pl];
  }
  __syncthreads();
  const int pl = tid & 63;
  const int vq = tid >> 6;
  short8 s;
#pragma unroll
  for (int j = 0; j < 8; ++j)
    s[j] = __builtin_bit_cast(short, __float2bfloat16(t[vq * 8 + j][pl]));
  *reinterpret_cast<short8*>(
      (short*)attb + ((size_t)nImg * PQ + p0 + pl) * 256 + hd * 32 + vq * 8) = s;
}

// ---------------------------------------------------------------------------
// MFMA GEMM: output projection + bias + gamma + residual; 32-wide p-tiles.
// Math identical to R12's gemm_out (truncated to 2 B-frags); grid (128,4,2).
// ---------------------------------------------------------------------------
__global__ __launch_bounds__(256) void gemm_out_kernel(
    const __hip_bfloat16* __restrict__ attb,
    const __hip_bfloat16* __restrict__ pw, const float* __restrict__ pb,
    const float* __restrict__ gamma, const float* __restrict__ x_in,
    float* __restrict__ out) {
  const int p0 = blockIdx.x * 32;
  const int o0 = blockIdx.y * 64;
  const int n = blockIdx.z;
  const int tid = threadIdx.x;
  const int wv = tid >> 6, l = tid & 63, lc = l & 15, lq = l >> 4;
  const short* ar =
      (const short*)pw + ((size_t)(o0 + wv * 16 + lc)) * 256 + 8 * lq;
  const short* bbase = (const short*)attb + ((size_t)n * PQ + p0) * 256 + 8 * lq;
  const short* b0p = bbase + (size_t)(0 + lc) * 256;
  const short* b1p = bbase + (size_t)(16 + lc) * 256;
  f32x4 acc0 = {0.f, 0.f, 0.f, 0.f};
  f32x4 acc1 = {0.f, 0.f, 0.f, 0.f};
#pragma unroll
  for (int kt = 0; kt < 8; ++kt) {
    const short8 af = *reinterpret_cast<const short8*>(ar + kt * 32);
    acc0 = __builtin_amdgcn_mfma_f32_16x16x32_bf16(
        af, *reinterpret_cast<const short8*>(b0p + kt * 32), acc0, 0, 0, 0);
    acc1 = __builtin_amdgcn_mfma_f32_16x16x32_bf16(
        af, *reinterpret_cast<const short8*>(b1p + kt * 32), acc1, 0, 0, 0);
  }
  const float gm = gamma[0];
#pragma unroll
  for (int r = 0; r < 4; ++r) {
    const int o = o0 + wv * 16 + 4 * lq + r;   // C row = 4*lq + r
    const float bo = pb[o];
    const size_t obase = ((size_t)n * 256 + o) * PQ;
    const size_t i0 = obase + (p0 + 0 + lc);
    const size_t i1 = obase + (p0 + 16 + lc);
    out[i0] = fmaf(gm, acc0[r] + bo, x_in[i0]);
    out[i1] = fmaf(gm, acc1[r] + bo, x_in[i1]);
  }
}

// ---------------------------------------------------------------------------
extern "C" void kernel_launch(void* const* d_in, const int* in_sizes, int n_in,
                              void* d_out, int out_size, void* d_ws,
                              size_t ws_size, hipStream_t stream) {
  const float* x = (const float*)d_in[0];
  const float* q_w = (const float*)d_in[1];
  const float* k_w = (const float*)d_in[2];
  const float* v_w = (const float*)d_in[3];
  const float* fcx_w = (const float*)d_in[4];
  const float* fcy_w = (const float*)d_in[5];
  const float* ab = (const float*)d_in[6];
  const float* gb = (const float*)d_in[7];
  const float* proj_w = (const float*)d_in[8];
  const float* proj_b = (const float*)d_in[9];
  const float* gamma = (const float*)d_in[10];
  float* out = (float*)d_out;

  float* ws = (float*)d_ws;
  float* att = ws;                       // 2,097,152 f
  float* EX = att + 2097152;             // 2,359,296 f
  float* EY = EX + 2359296;              // 1,310,720 f
  __hip_bfloat16* bp = (__hip_bfloat16*)(EY + 1310720);
  __hip_bfloat16* qab_b = bp;   bp += 2097152;
  __hip_bfloat16* qgb_b = bp;   bp += 2097152;
  __hip_bfloat16* k_lb = bp;    bp += 524288;
  __hip_bfloat16* v_t = bp;     bp += 524288;
  __hip_bfloat16* pembx_b = bp; bp += 32256;
  __hip_bfloat16* pemby_b = bp; bp += 32256;
  __hip_bfloat16* qw_b = bp;    bp += 65536;
  __hip_bfloat16* kw_b = bp;    bp += 65536;
  __hip_bfloat16* vw_b = bp;    bp += 65536;
  __hip_bfloat16* pw_b = bp;    bp += 65536;
  __hip_bfloat16* xb = bp;      bp += 2097152;
  __hip_bfloat16* attb = bp;    bp += 2097152;
  // total = 42.6 MB (R12-proven layout, unchanged)

  prep_kernel<<<dim3(508), 256, 0, stream>>>(q_w, k_w, v_w, proj_w, qw_b,
                                             kw_b, vw_b, pw_b, fcx_w, fcy_w,
                                             pembx_b, pemby_b);
  xpose_kernel<<<dim3(64, 4, 2), 256, 0, stream>>>(x, xb);
  gemm_qkv_kernel<<<dim3(1536), 256, 0, stream>>>(xb, qw_b, kw_b, vw_b, ab,
                                                  gb, qab_b, qgb_b, k_lb, v_t);
  exy_kernel<<<dim3(64, 16, 2), 256, 0, stream>>>(qgb_b, pembx_b, pemby_b, EX,
                                                  EY);
  attn_mfma_kernel<<<dim3(64, 16), 512, 0, stream>>>(qab_b, k_lb, v_t, EX, EY,
                                                     att);
  att2b_kernel<<<dim3(64, 16), 256, 0, stream>>>(att, attb);
  gemm_out_kernel<<<dim3(128, 4, 2), 256, 0, stream>>>(attb, pw_b, proj_b,
                                                       gamma, x, out);
}

// Round 14
// 88.713 us; speedup vs baseline: 1.1418x; 1.0802x over previous
//
#include <hip/hip_runtime.h>
#include <hip/hip_bf16.h>
#include <math.h>

// Problem sizes (fixed by the reference)
#define NB   2
#define CC   256
#define PQ   4096   // 64*64 queries per image
#define PKV  1024   // 32*32 kv per image

#define NF (-INFINITY)
#define M0 24.0f    // fixed softmax offset (baked into EX; |e| << 80)
#define EXSTRIDE 36
#define EYSTRIDE 20

typedef __attribute__((ext_vector_type(8))) short short8;
typedef __attribute__((ext_vector_type(4))) float f32x4;

// ---------------------------------------------------------------------------
// Fused prep: blocks 0..255 weights fp32->bf16; 256..507 posfeat pemb tables;
// 508..1019 x transpose to bf16 pixel-major xb[n][p][c].
// ---------------------------------------------------------------------------
__global__ __launch_bounds__(256) void prep_kernel(
    const float* __restrict__ q_w, const float* __restrict__ k_w,
    const float* __restrict__ v_w, const float* __restrict__ proj_w,
    __hip_bfloat16* __restrict__ qw_b, __hip_bfloat16* __restrict__ kw_b,
    __hip_bfloat16* __restrict__ vw_b, __hip_bfloat16* __restrict__ pw_b,
    const float* __restrict__ fcx, const float* __restrict__ fcy,
    __hip_bfloat16* __restrict__ pembx_b, __hip_bfloat16* __restrict__ pemby_b,
    const float* __restrict__ x, __hip_bfloat16* __restrict__ xb) {
  __shared__ __align__(16) float shbuf[64 * 65];
  const int bid = blockIdx.x;
  const int tid = threadIdx.x;
  if (bid < 256) {
    const int which = bid >> 6;
    const float* src = (which == 0) ? q_w : (which == 1) ? k_w
                       : (which == 2) ? v_w : proj_w;
    __hip_bfloat16* dst = (which == 0) ? qw_b : (which == 1) ? kw_b
                          : (which == 2) ? vw_b : pw_b;
    const int i = (bid & 63) * 256 + tid;
    const float4 v = reinterpret_cast<const float4*>(src)[i];
    short4 s;
    s.x = __builtin_bit_cast(short, __float2bfloat16(v.x));
    s.y = __builtin_bit_cast(short, __float2bfloat16(v.y));
    s.z = __builtin_bit_cast(short, __float2bfloat16(v.z));
    s.w = __builtin_bit_cast(short, __float2bfloat16(v.w));
    reinterpret_cast<short4*>(dst)[i] = s;
  } else if (bid < 508) {
    float* feat = shbuf;
    const int pb = bid - 256;        // 0..251
    const int dd = pb >> 1;          // 0..125 -> diff = dd - 62
    const int which = pb & 1;
    const float* FC = which ? fcy : fcx;
    __hip_bfloat16* OUT = which ? pemby_b : pembx_b;
    if (tid < 64) {
      const float diff = (float)(dd - 62);
      const float dm = powf(1000.f, (float)tid * (1.f / 64.f));
      const float aa = diff / dm;
      feat[tid] = sinf(aa);
      feat[tid + 64] = cosf(aa);
    }
    __syncthreads();
    const float4* row4 = reinterpret_cast<const float4*>(FC + tid * 128);
    const float4* f4 = reinterpret_cast<const float4*>(feat);
    float s0 = 0.f, s1 = 0.f, s2 = 0.f, s3 = 0.f;
#pragma unroll
    for (int f = 0; f < 32; ++f) {
      const float4 fv = f4[f];
      const float4 rv = row4[f];
      s0 = fmaf(fv.x, rv.x, s0);
      s1 = fmaf(fv.y, rv.y, s1);
      s2 = fmaf(fv.z, rv.z, s2);
      s3 = fmaf(fv.w, rv.w, s3);
    }
    const float s = ((s0 + s1) + (s2 + s3)) * 0.70710678118654752440f;
    OUT[(size_t)dd * 256 + tid] = __float2bfloat16(s);
  } else {
    // xpose branch (R13 xpose_kernel body, block decode b = bid-508)
    float (*t)[65] = reinterpret_cast<float(*)[65]>(shbuf);
    const int b = bid - 508;
    const int p0 = (b & 63) * 64;
    const int c0 = ((b >> 6) & 3) * 64;
    const int n = b >> 8;
    {
      const int pl = tid & 63, cg = tid >> 6;
#pragma unroll
      for (int i = 0; i < 16; ++i) {
        const int cl = cg * 16 + i;
        t[cl][pl] = x[((size_t)n * 256 + c0 + cl) * PQ + p0 + pl];
      }
    }
    __syncthreads();
    const int cl = tid & 63;
#pragma unroll
    for (int j = 0; j < 16; ++j) {
      const int pl = (tid >> 6) + 4 * j;
      ((__hip_bfloat16*)xb)[((size_t)n * PQ + p0 + pl) * 256 + c0 + cl] =
          __float2bfloat16(t[cl][pl]);
    }
  }
}

// ---------------------------------------------------------------------------
// Fused Q + K/V projection GEMMs (R13-proven, unchanged).
// ---------------------------------------------------------------------------
__global__ __launch_bounds__(256) void gemm_qkv_kernel(
    const __hip_bfloat16* __restrict__ xb,
    const __hip_bfloat16* __restrict__ qw, const __hip_bfloat16* __restrict__ kw,
    const __hip_bfloat16* __restrict__ vw, const float* __restrict__ ab,
    const float* __restrict__ gb, __hip_bfloat16* __restrict__ qab,
    __hip_bfloat16* __restrict__ qgb, __hip_bfloat16* __restrict__ k_lb,
    __hip_bfloat16* __restrict__ v_t) {
  const int bid = blockIdx.x;
  const int tid = threadIdx.x;
  const int wv = tid >> 6, l = tid & 63, lc = l & 15, lq = l >> 4;
  if (bid < 1024) {
    const int n = bid & 1;
    const int o0 = ((bid >> 1) & 3) * 64;
    const int p0 = (bid >> 3) * 32;
    const short* ar =
        (const short*)qw + ((size_t)(o0 + wv * 16 + lc)) * 256 + 8 * lq;
    const short* bbase =
        (const short*)xb + ((size_t)n * PQ + p0) * 256 + 8 * lq;
    const short* b0p = bbase + (size_t)(0 + lc) * 256;
    const short* b1p = bbase + (size_t)(16 + lc) * 256;
    f32x4 acc0 = {0.f, 0.f, 0.f, 0.f};
    f32x4 acc1 = {0.f, 0.f, 0.f, 0.f};
#pragma unroll
    for (int kt = 0; kt < 8; ++kt) {
      const short8 af = *reinterpret_cast<const short8*>(ar + kt * 32);
      acc0 = __builtin_amdgcn_mfma_f32_16x16x32_bf16(
          af, *reinterpret_cast<const short8*>(b0p + kt * 32), acc0, 0, 0, 0);
      acc1 = __builtin_amdgcn_mfma_f32_16x16x32_bf16(
          af, *reinterpret_cast<const short8*>(b1p + kt * 32), acc1, 0, 0, 0);
    }
#pragma unroll
    for (int r = 0; r < 4; ++r) {
      const int o = o0 + wv * 16 + 4 * lq + r;
      const float abo = ab[o], gbo = gb[o];
      const int head = o >> 5, dd = o & 31;
      const size_t gbase = (size_t)(n * 8 + head) * PQ;
      const float a_[2] = {acc0[r], acc1[r]};
#pragma unroll
      for (int nf = 0; nf < 2; ++nf) {
        const int p = p0 + 16 * nf + lc;
        const size_t idx = (gbase + p) * 32 + dd;
        qab[idx] = __float2bfloat16(a_[nf] + abo);
        qgb[idx] = __float2bfloat16(a_[nf] + gbo);
      }
    }
  } else {
    const int kb2 = bid - 1024;
    const int n = kb2 & 1;
    const int o0 = ((kb2 >> 1) & 3) * 64;
    const bool isV = ((kb2 >> 3) & 1) != 0;
    const int p0 = (kb2 >> 4) * 32;
    const __hip_bfloat16* W = isV ? vw : kw;
    const short* ar =
        (const short*)W + ((size_t)(o0 + wv * 16 + lc)) * 256 + 8 * lq;
    const short* bb = (const short*)xb + (size_t)n * PQ * 256 + 8 * lq;
    const int pk0 = p0 + 0 + lc, pk1 = p0 + 16 + lc;
    const short* b0p = bb + (size_t)((pk0 >> 5) * 128 + (pk0 & 31) * 2) * 256;
    const short* b1p = bb + (size_t)((pk1 >> 5) * 128 + (pk1 & 31) * 2) * 256;
    f32x4 acc0 = {0.f, 0.f, 0.f, 0.f};
    f32x4 acc1 = {0.f, 0.f, 0.f, 0.f};
#pragma unroll
    for (int kt = 0; kt < 8; ++kt) {
      const short8 af = *reinterpret_cast<const short8*>(ar + kt * 32);
      acc0 = __builtin_amdgcn_mfma_f32_16x16x32_bf16(
          af, *reinterpret_cast<const short8*>(b0p + kt * 32), acc0, 0, 0, 0);
      acc1 = __builtin_amdgcn_mfma_f32_16x16x32_bf16(
          af, *reinterpret_cast<const short8*>(b1p + kt * 32), acc1, 0, 0, 0);
    }
#pragma unroll
    for (int r = 0; r < 4; ++r) {
      const int o = o0 + wv * 16 + 4 * lq + r;
      const int head = o >> 5, dd = o & 31;
      const float a_[2] = {acc0[r], acc1[r]};
#pragma unroll
      for (int nf = 0; nf < 2; ++nf) {
        const int p = p0 + 16 * nf + lc;
        if (!isV) {
          k_lb[((size_t)(n * 8 + head) * PKV + p) * 32 + dd] =
              __float2bfloat16(a_[nf]);
        } else {
          v_t[((size_t)(n * 8 + head) * 32 + dd) * PKV + p] =
              __float2bfloat16(a_[nf]);
        }
      }
    }
  }
}

// ---------------------------------------------------------------------------
// Positional energy tables via MFMA; fused modes (R13-proven, unchanged).
// ---------------------------------------------------------------------------
__global__ __launch_bounds__(256) void exy_kernel(
    const __hip_bfloat16* __restrict__ qgb_b,
    const __hip_bfloat16* __restrict__ pembx_b,
    const __hip_bfloat16* __restrict__ pemby_b, float* __restrict__ EX,
    float* __restrict__ EY) {
  const int MODE = blockIdx.z;
  const int i = blockIdx.x;       // x (MODE0) or y (MODE1)
  const int g = blockIdx.y;
  const int head = g & 7;
  const __hip_bfloat16* pemb_b = MODE ? pemby_b : pembx_b;
  const int wv = threadIdx.x >> 6;
  const int l = threadIdx.x & 63;
  const int lc = l & 15, lq = l >> 4;

  const int rowi = wv * 16 + lc;  // y (MODE0) or x (MODE1)
  const int p = (MODE == 0) ? rowi * 64 + i : i * 64 + rowi;
  const short8 a = *reinterpret_cast<const short8*>(
      (const short*)qgb_b + ((size_t)g * PQ + p) * 32 + 8 * lq);

  int drow0, drow1;
  if (MODE == 0) {
    drow0 = i - 2 * lc + 62;
    drow1 = i - 2 * (lc + 16) + 62;
  } else {
    const int lo_y = max((i - 16) >> 1, 0);
    drow0 = i - 2 * (lo_y + lc) + 62;
    drow1 = i - 2 * (lo_y + lc + 16) + 62;
  }
  const short8 b0 = *reinterpret_cast<const short8*>(
      (const short*)pemb_b + (size_t)drow0 * 256 + head * 32 + 8 * lq);
  const short8 b1 = *reinterpret_cast<const short8*>(
      (const short*)pemb_b + (size_t)drow1 * 256 + head * 32 + 8 * lq);

  const f32x4 zero = {0.f, 0.f, 0.f, 0.f};
  const f32x4 c0 = __builtin_amdgcn_mfma_f32_16x16x32_bf16(a, b0, zero, 0, 0, 0);
  const f32x4 c1 = __builtin_amdgcn_mfma_f32_16x16x32_bf16(a, b1, zero, 0, 0, 0);

#pragma unroll
  for (int r = 0; r < 4; ++r) {
    const int rowr = wv * 16 + 4 * lq + r;
    const int pr = (MODE == 0) ? rowr * 64 + i : i * 64 + rowr;
    if (MODE == 0) {
      const int lox = max((i - 16) >> 1, 0);
      const int hix = min(((i + 17) >> 1) + 1, 32);
      float* o = EX + ((size_t)g * PQ + pr) * EXSTRIDE;
      o[lc] = (lc >= lox && lc < hix) ? (c0[r] - M0) : -1e30f;
      o[16 + lc] = (lc + 16 >= lox && lc + 16 < hix) ? (c1[r] - M0) : -1e30f;
      if (lc < 4) o[32 + lc] = -1e30f;
    } else {
      float* o = EY + ((size_t)g * PQ + pr) * EYSTRIDE;
      o[lc] = c0[r];
      if (lc < 4) o[16 + lc] = c1[r];
    }
  }
}

// ---------------------------------------------------------------------------
// MFMA local-window attention, 8-wave ky-parity split; epilogue now fuses
// att2b: O*inv -> wave-private LDS fp32 transpose -> bf16 attb[n][p][c]
// (structurally identical to the proven att2b path; same rounding sequence).
// ---------------------------------------------------------------------------
__global__ __launch_bounds__(512, 8) void attn_mfma_kernel(
    const __hip_bfloat16* __restrict__ qab_b,
    const __hip_bfloat16* __restrict__ k_lb,
    const __hip_bfloat16* __restrict__ v_t, const float* __restrict__ EX,
    const float* __restrict__ EY, __hip_bfloat16* __restrict__ attb) {
  const int g = blockIdx.y;    // n*8 + head
  const int nImg = g >> 3, hd = g & 7;
  const int bx = blockIdx.x & 3;   // x-tile of 16
  const int by = blockIdx.x >> 2;  // y-tile of 4 rows
  const int tx = bx * 16;
  const int wv = threadIdx.x >> 6;   // 0..7
  const int yw = wv & 3;             // y-row within tile
  const int s = wv >> 2;             // ky parity
  const int y = by * 4 + yw;
  const int l = threadIdx.x & 63;
  const int lc = l & 15;   // col lane (q for S^T / vd for O)
  const int lq = l >> 4;   // quarter

  __shared__ float eybuf[4][EYSTRIDE][16];  // [yrow][t][q]
  __shared__ float mrg[4][64][9];           // [yrow][lane][acc0*4,acc1*4,lp]
  __shared__ float obuf[4][16][33];         // [yrow][q][vd] fp32 O*inv

  const int KLO = max((tx - 16) >> 1, 0);
  const int lo_y = max((y - 16) >> 1, 0);
  const int hi_y = min(((y + 17) >> 1) + 1, 32);
  const int NKY = hi_y - lo_y;

  const int xq = tx + lc;
  const int pq_ = y * 64 + xq;

  // Qa B-frag: lane holds Qa[d=8lq+j][q=lc]
  const short8 qa = *reinterpret_cast<const short8*>(
      (const short*)qab_b + ((size_t)g * PQ + pq_) * 32 + 8 * lq);

  // per-lane loop-invariant ex registers (mask, M0, x-positional term baked)
  const float* exr = EX + ((size_t)g * PQ + pq_) * EXSTRIDE;
  float exC0[4], exC1[4];
#pragma unroll
  for (int r = 0; r < 4; ++r) {
    exC0[r] = exr[KLO + 4 * lq + r];
    exC1[r] = exr[min(KLO + 16 + 4 * lq + r, 35)];
  }

  // ey -> LDS ([t][q] layout); written once per y-row by waves 0-3
  if (wv < 4) {
    const float* eyr = EY + ((size_t)g * PQ + pq_) * EYSTRIDE;
    const float4 e4 = *reinterpret_cast<const float4*>(eyr + 4 * lq);
#pragma unroll
    for (int j = 0; j < 4; ++j) eybuf[yw][4 * lq + j][lc] = e4[j];
    if (lq == 0) {
      const float4 e4b = *reinterpret_cast<const float4*>(eyr + 16);
#pragma unroll
      for (int j = 0; j < 4; ++j) eybuf[yw][16 + j][lc] = e4b[j];
    }
  }
  __syncthreads();

  const __hip_bfloat16* kb =
      k_lb + ((size_t)g * PKV + (size_t)lo_y * 32) * 32;
  const __hip_bfloat16* kb0 = kb + (KLO + lc) * 32 + 8 * lq;
  const __hip_bfloat16* kb1 = kb + min(KLO + 16 + lc, 31) * 32 + 8 * lq;
  const __hip_bfloat16* vb0 =
      v_t + ((size_t)g * 32 + lc) * PKV + (size_t)lo_y * 32 + KLO + 8 * lq;
  const __hip_bfloat16* vb1 = vb0 + 16 * PKV;

  f32x4 acc0 = {0.f, 0.f, 0.f, 0.f};
  f32x4 acc1 = {0.f, 0.f, 0.f, 0.f};
  float lp = 0.f;
  const int srcA = lc + ((l & 16) << 1);  // lane lc + 32*(lq&1)
  const int srcB = srcA + 16;
  const bool hiL = (l & 32) != 0;

#pragma unroll 1
  for (int t = s; t < NKY; t += 2) {
    const short8 k0 = *reinterpret_cast<const short8*>(kb0 + t * 1024);
    const short8 k1 = *reinterpret_cast<const short8*>(kb1 + t * 1024);
    const short8 v0 = *reinterpret_cast<const short8*>(vb0 + t * 32);
    const short8 v1 = *reinterpret_cast<const short8*>(vb1 + t * 32);
    const f32x4 zero = {0.f, 0.f, 0.f, 0.f};
    // S^T tiles: rows kx_local = 4*lq + r, cols q = lc
    const f32x4 s0 = __builtin_amdgcn_mfma_f32_16x16x32_bf16(k0, qa, zero, 0, 0, 0);
    const f32x4 s1 = __builtin_amdgcn_mfma_f32_16x16x32_bf16(k1, qa, zero, 0, 0, 0);
    const float eyC = eybuf[yw][t][lc];
    float p0[4], p1[4];
#pragma unroll
    for (int r = 0; r < 4; ++r) {
      p0[r] = __expf(s0[r] + exC0[r] + eyC);   // masked: exC=-1e30 -> 0
      p1[r] = __expf(s1[r] + exC1[r] + eyC);
    }
    lp += ((p0[0] + p0[1]) + (p0[2] + p0[3])) +
          ((p1[0] + p1[1]) + (p1[2] + p1[3]));
    int w00, w01, w10, w11;
    asm("v_cvt_pk_bf16_f32 %0, %1, %2" : "=v"(w00) : "v"(p0[0]), "v"(p0[1]));
    asm("v_cvt_pk_bf16_f32 %0, %1, %2" : "=v"(w01) : "v"(p0[2]), "v"(p0[3]));
    asm("v_cvt_pk_bf16_f32 %0, %1, %2" : "=v"(w10) : "v"(p1[0]), "v"(p1[1]));
    asm("v_cvt_pk_bf16_f32 %0, %1, %2" : "=v"(w11) : "v"(p1[2]), "v"(p1[3]));
    const int a0 = __shfl(w00, srcA, 64), b0 = __shfl(w10, srcA, 64);
    const int a1 = __shfl(w01, srcA, 64), b1 = __shfl(w11, srcA, 64);
    const int a2 = __shfl(w00, srcB, 64), b2 = __shfl(w10, srcB, 64);
    const int a3 = __shfl(w01, srcB, 64), b3 = __shfl(w11, srcB, 64);
    int4 pw;
    pw.x = hiL ? b0 : a0;
    pw.y = hiL ? b1 : a1;
    pw.z = hiL ? b2 : a2;
    pw.w = hiL ? b3 : a3;
    const short8 pf = __builtin_bit_cast(short8, pw);
    acc0 = __builtin_amdgcn_mfma_f32_16x16x32_bf16(pf, v0, acc0, 0, 0, 0);
    acc1 = __builtin_amdgcn_mfma_f32_16x16x32_bf16(pf, v1, acc1, 0, 0, 0);
  }

  // pair-merge: parity-1 waves deposit (acc, lp); parity-0 waves add.
  if (s == 1) {
    float* m = mrg[yw][l];
#pragma unroll
    for (int r = 0; r < 4; ++r) m[r] = acc0[r];
#pragma unroll
    for (int r = 0; r < 4; ++r) m[4 + r] = acc1[r];
    m[8] = lp;
  }
  __syncthreads();
  if (s == 1) return;
  {
    const float* m = mrg[yw][l];
#pragma unroll
    for (int r = 0; r < 4; ++r) acc0[r] += m[r];
#pragma unroll
    for (int r = 0; r < 4; ++r) acc1[r] += m[4 + r];
    lp += m[8];
  }

  // l: sum over the 4 lq groups -> every lane holds L[q=lc]
  lp += __shfl_xor(lp, 16);
  lp += __shfl_xor(lp, 32);
  const float invall = 1.f / lp;

  // fused att2b epilogue: O*inv -> obuf (wave-private yw slice) -> bf16 attb
#pragma unroll
  for (int r = 0; r < 4; ++r) {
    const float inv = __shfl(invall, 4 * lq + r, 16);  // L for q = 4lq+r
    obuf[yw][4 * lq + r][lc] = acc0[r] * inv;
    obuf[yw][4 * lq + r][16 + lc] = acc1[r] * inv;
  }
  // readback: lane l -> pixel q = l>>2, channel chunk (l&3)*8 (conflict-free)
  const int qp = l >> 2;
  const int ch = (l & 3) * 8;
  short8 sv;
#pragma unroll
  for (int j = 0; j < 8; ++j)
    sv[j] = __builtin_bit_cast(short, __float2bfloat16(obuf[yw][qp][ch + j]));
  const int p = y * 64 + tx + qp;
  *reinterpret_cast<short8*>(
      (short*)attb + ((size_t)nImg * PQ + p) * 256 + hd * 32 + ch) = sv;
}

// ---------------------------------------------------------------------------
// MFMA GEMM: output projection + bias + gamma + residual (R13-proven).
// ---------------------------------------------------------------------------
__global__ __launch_bounds__(256) void gemm_out_kernel(
    const __hip_bfloat16* __restrict__ attb,
    const __hip_bfloat16* __restrict__ pw, const float* __restrict__ pb,
    const float* __restrict__ gamma, const float* __restrict__ x_in,
    float* __restrict__ out) {
  const int p0 = blockIdx.x * 32;
  const int o0 = blockIdx.y * 64;
  const int n = blockIdx.z;
  const int tid = threadIdx.x;
  const int wv = tid >> 6, l = tid & 63, lc = l & 15, lq = l >> 4;
  const short* ar =
      (const short*)pw + ((size_t)(o0 + wv * 16 + lc)) * 256 + 8 * lq;
  const short* bbase = (const short*)attb + ((size_t)n * PQ + p0) * 256 + 8 * lq;
  const short* b0p = bbase + (size_t)(0 + lc) * 256;
  const short* b1p = bbase + (size_t)(16 + lc) * 256;
  f32x4 acc0 = {0.f, 0.f, 0.f, 0.f};
  f32x4 acc1 = {0.f, 0.f, 0.f, 0.f};
#pragma unroll
  for (int kt = 0; kt < 8; ++kt) {
    const short8 af = *reinterpret_cast<const short8*>(ar + kt * 32);
    acc0 = __builtin_amdgcn_mfma_f32_16x16x32_bf16(
        af, *reinterpret_cast<const short8*>(b0p + kt * 32), acc0, 0, 0, 0);
    acc1 = __builtin_amdgcn_mfma_f32_16x16x32_bf16(
        af, *reinterpret_cast<const short8*>(b1p + kt * 32), acc1, 0, 0, 0);
  }
  const float gm = gamma[0];
#pragma unroll
  for (int r = 0; r < 4; ++r) {
    const int o = o0 + wv * 16 + 4 * lq + r;   // C row = 4*lq + r
    const float bo = pb[o];
    const size_t obase = ((size_t)n * 256 + o) * PQ;
    const size_t i0 = obase + (p0 + 0 + lc);
    const size_t i1 = obase + (p0 + 16 + lc);
    out[i0] = fmaf(gm, acc0[r] + bo, x_in[i0]);
    out[i1] = fmaf(gm, acc1[r] + bo, x_in[i1]);
  }
}

// ---------------------------------------------------------------------------
extern "C" void kernel_launch(void* const* d_in, const int* in_sizes, int n_in,
                              void* d_out, int out_size, void* d_ws,
                              size_t ws_size, hipStream_t stream) {
  const float* x = (const float*)d_in[0];
  const float* q_w = (const float*)d_in[1];
  const float* k_w = (const float*)d_in[2];
  const float* v_w = (const float*)d_in[3];
  const float* fcx_w = (const float*)d_in[4];
  const float* fcy_w = (const float*)d_in[5];
  const float* ab = (const float*)d_in[6];
  const float* gb = (const float*)d_in[7];
  const float* proj_w = (const float*)d_in[8];
  const float* proj_b = (const float*)d_in[9];
  const float* gamma = (const float*)d_in[10];
  float* out = (float*)d_out;

  float* ws = (float*)d_ws;
  float* EX = ws;                        // 2,359,296 f
  float* EY = EX + 2359296;              // 1,310,720 f
  __hip_bfloat16* bp = (__hip_bfloat16*)(EY + 1310720);
  __hip_bfloat16* qab_b = bp;   bp += 2097152;
  __hip_bfloat16* qgb_b = bp;   bp += 2097152;
  __hip_bfloat16* k_lb = bp;    bp += 524288;
  __hip_bfloat16* v_t = bp;     bp += 524288;
  __hip_bfloat16* pembx_b = bp; bp += 32256;
  __hip_bfloat16* pemby_b = bp; bp += 32256;
  __hip_bfloat16* qw_b = bp;    bp += 65536;
  __hip_bfloat16* kw_b = bp;    bp += 65536;
  __hip_bfloat16* vw_b = bp;    bp += 65536;
  __hip_bfloat16* pw_b = bp;    bp += 65536;
  __hip_bfloat16* xb = bp;      bp += 2097152;
  __hip_bfloat16* attb = bp;    bp += 2097152;
  // total = 3,670,016 f + 9,763,840 bf16 = 34.2 MB (< R13's proven 42.6)

  prep_kernel<<<dim3(1020), 256, 0, stream>>>(q_w, k_w, v_w, proj_w, qw_b,
                                              kw_b, vw_b, pw_b, fcx_w, fcy_w,
                                              pembx_b, pemby_b, x, xb);
  gemm_qkv_kernel<<<dim3(1536), 256, 0, stream>>>(xb, qw_b, kw_b, vw_b, ab,
                                                  gb, qab_b, qgb_b, k_lb, v_t);
  exy_kernel<<<dim3(64, 16, 2), 256, 0, stream>>>(qgb_b, pembx_b, pemby_b, EX,
                                                  EY);
  attn_mfma_kernel<<<dim3(64, 16), 512, 0, stream>>>(qab_b, k_lb, v_t, EX, EY,
                                                     attb);
  gemm_out_kernel<<<dim3(128, 4, 2), 256, 0, stream>>>(attb, pw_b, proj_b,
                                                       gamma, x, out);
}

// Round 15
// 86.051 us; speedup vs baseline: 1.1771x; 1.0309x over previous
//
#include <hip/hip_runtime.h>
#include <hip/hip_bf16.h>
#include <math.h>

// Problem sizes (fixed by the reference)
#define NB   2
#define CC   256
#define PQ   4096   // 64*64 queries per image
#define PKV  1024   // 32*32 kv per image

#define NF (-INFINITY)
#define M0 24.0f    // fixed softmax offset (baked into EX; |e| << 80)
#define EXSTRIDE 36
#define EYSTRIDE 20

typedef __attribute__((ext_vector_type(8))) short short8;
typedef __attribute__((ext_vector_type(4))) float f32x4;

// ---------------------------------------------------------------------------
// Fused prep: blocks 0..255 weights fp32->bf16; 256..507 posfeat pemb tables;
// 508..1019 x transpose to bf16 pixel-major xb[n][p][c]. (R14-proven)
// ---------------------------------------------------------------------------
__global__ __launch_bounds__(256) void prep_kernel(
    const float* __restrict__ q_w, const float* __restrict__ k_w,
    const float* __restrict__ v_w, const float* __restrict__ proj_w,
    __hip_bfloat16* __restrict__ qw_b, __hip_bfloat16* __restrict__ kw_b,
    __hip_bfloat16* __restrict__ vw_b, __hip_bfloat16* __restrict__ pw_b,
    const float* __restrict__ fcx, const float* __restrict__ fcy,
    __hip_bfloat16* __restrict__ pembx_b, __hip_bfloat16* __restrict__ pemby_b,
    const float* __restrict__ x, __hip_bfloat16* __restrict__ xb) {
  __shared__ __align__(16) float shbuf[64 * 65];
  const int bid = blockIdx.x;
  const int tid = threadIdx.x;
  if (bid < 256) {
    const int which = bid >> 6;
    const float* src = (which == 0) ? q_w : (which == 1) ? k_w
                       : (which == 2) ? v_w : proj_w;
    __hip_bfloat16* dst = (which == 0) ? qw_b : (which == 1) ? kw_b
                          : (which == 2) ? vw_b : pw_b;
    const int i = (bid & 63) * 256 + tid;
    const float4 v = reinterpret_cast<const float4*>(src)[i];
    short4 s;
    s.x = __builtin_bit_cast(short, __float2bfloat16(v.x));
    s.y = __builtin_bit_cast(short, __float2bfloat16(v.y));
    s.z = __builtin_bit_cast(short, __float2bfloat16(v.z));
    s.w = __builtin_bit_cast(short, __float2bfloat16(v.w));
    reinterpret_cast<short4*>(dst)[i] = s;
  } else if (bid < 508) {
    float* feat = shbuf;
    const int pb = bid - 256;        // 0..251
    const int dd = pb >> 1;          // 0..125 -> diff = dd - 62
    const int which = pb & 1;
    const float* FC = which ? fcy : fcx;
    __hip_bfloat16* OUT = which ? pemby_b : pembx_b;
    if (tid < 64) {
      const float diff = (float)(dd - 62);
      const float dm = powf(1000.f, (float)tid * (1.f / 64.f));
      const float aa = diff / dm;
      feat[tid] = sinf(aa);
      feat[tid + 64] = cosf(aa);
    }
    __syncthreads();
    const float4* row4 = reinterpret_cast<const float4*>(FC + tid * 128);
    const float4* f4 = reinterpret_cast<const float4*>(feat);
    float s0 = 0.f, s1 = 0.f, s2 = 0.f, s3 = 0.f;
#pragma unroll
    for (int f = 0; f < 32; ++f) {
      const float4 fv = f4[f];
      const float4 rv = row4[f];
      s0 = fmaf(fv.x, rv.x, s0);
      s1 = fmaf(fv.y, rv.y, s1);
      s2 = fmaf(fv.z, rv.z, s2);
      s3 = fmaf(fv.w, rv.w, s3);
    }
    const float s = ((s0 + s1) + (s2 + s3)) * 0.70710678118654752440f;
    OUT[(size_t)dd * 256 + tid] = __float2bfloat16(s);
  } else {
    float (*t)[65] = reinterpret_cast<float(*)[65]>(shbuf);
    const int b = bid - 508;
    const int p0 = (b & 63) * 64;
    const int c0 = ((b >> 6) & 3) * 64;
    const int n = b >> 8;
    {
      const int pl = tid & 63, cg = tid >> 6;
#pragma unroll
      for (int i = 0; i < 16; ++i) {
        const int cl = cg * 16 + i;
        t[cl][pl] = x[((size_t)n * 256 + c0 + cl) * PQ + p0 + pl];
      }
    }
    __syncthreads();
    const int cl = tid & 63;
#pragma unroll
    for (int j = 0; j < 16; ++j) {
      const int pl = (tid >> 6) + 4 * j;
      ((__hip_bfloat16*)xb)[((size_t)n * PQ + p0 + pl) * 256 + c0 + cl] =
          __float2bfloat16(t[cl][pl]);
    }
  }
}

// ---------------------------------------------------------------------------
// Fused Q + K/V projection GEMMs (R14-proven, unchanged).
// ---------------------------------------------------------------------------
__global__ __launch_bounds__(256) void gemm_qkv_kernel(
    const __hip_bfloat16* __restrict__ xb,
    const __hip_bfloat16* __restrict__ qw, const __hip_bfloat16* __restrict__ kw,
    const __hip_bfloat16* __restrict__ vw, const float* __restrict__ ab,
    const float* __restrict__ gb, __hip_bfloat16* __restrict__ qab,
    __hip_bfloat16* __restrict__ qgb, __hip_bfloat16* __restrict__ k_lb,
    __hip_bfloat16* __restrict__ v_t) {
  const int bid = blockIdx.x;
  const int tid = threadIdx.x;
  const int wv = tid >> 6, l = tid & 63, lc = l & 15, lq = l >> 4;
  if (bid < 1024) {
    const int n = bid & 1;
    const int o0 = ((bid >> 1) & 3) * 64;
    const int p0 = (bid >> 3) * 32;
    const short* ar =
        (const short*)qw + ((size_t)(o0 + wv * 16 + lc)) * 256 + 8 * lq;
    const short* bbase =
        (const short*)xb + ((size_t)n * PQ + p0) * 256 + 8 * lq;
    const short* b0p = bbase + (size_t)(0 + lc) * 256;
    const short* b1p = bbase + (size_t)(16 + lc) * 256;
    f32x4 acc0 = {0.f, 0.f, 0.f, 0.f};
    f32x4 acc1 = {0.f, 0.f, 0.f, 0.f};
#pragma unroll
    for (int kt = 0; kt < 8; ++kt) {
      const short8 af = *reinterpret_cast<const short8*>(ar + kt * 32);
      acc0 = __builtin_amdgcn_mfma_f32_16x16x32_bf16(
          af, *reinterpret_cast<const short8*>(b0p + kt * 32), acc0, 0, 0, 0);
      acc1 = __builtin_amdgcn_mfma_f32_16x16x32_bf16(
          af, *reinterpret_cast<const short8*>(b1p + kt * 32), acc1, 0, 0, 0);
    }
#pragma unroll
    for (int r = 0; r < 4; ++r) {
      const int o = o0 + wv * 16 + 4 * lq + r;
      const float abo = ab[o], gbo = gb[o];
      const int head = o >> 5, dd = o & 31;
      const size_t gbase = (size_t)(n * 8 + head) * PQ;
      const float a_[2] = {acc0[r], acc1[r]};
#pragma unroll
      for (int nf = 0; nf < 2; ++nf) {
        const int p = p0 + 16 * nf + lc;
        const size_t idx = (gbase + p) * 32 + dd;
        qab[idx] = __float2bfloat16(a_[nf] + abo);
        qgb[idx] = __float2bfloat16(a_[nf] + gbo);
      }
    }
  } else {
    const int kb2 = bid - 1024;
    const int n = kb2 & 1;
    const int o0 = ((kb2 >> 1) & 3) * 64;
    const bool isV = ((kb2 >> 3) & 1) != 0;
    const int p0 = (kb2 >> 4) * 32;
    const __hip_bfloat16* W = isV ? vw : kw;
    const short* ar =
        (const short*)W + ((size_t)(o0 + wv * 16 + lc)) * 256 + 8 * lq;
    const short* bb = (const short*)xb + (size_t)n * PQ * 256 + 8 * lq;
    const int pk0 = p0 + 0 + lc, pk1 = p0 + 16 + lc;
    const short* b0p = bb + (size_t)((pk0 >> 5) * 128 + (pk0 & 31) * 2) * 256;
    const short* b1p = bb + (size_t)((pk1 >> 5) * 128 + (pk1 & 31) * 2) * 256;
    f32x4 acc0 = {0.f, 0.f, 0.f, 0.f};
    f32x4 acc1 = {0.f, 0.f, 0.f, 0.f};
#pragma unroll
    for (int kt = 0; kt < 8; ++kt) {
      const short8 af = *reinterpret_cast<const short8*>(ar + kt * 32);
      acc0 = __builtin_amdgcn_mfma_f32_16x16x32_bf16(
          af, *reinterpret_cast<const short8*>(b0p + kt * 32), acc0, 0, 0, 0);
      acc1 = __builtin_amdgcn_mfma_f32_16x16x32_bf16(
          af, *reinterpret_cast<const short8*>(b1p + kt * 32), acc1, 0, 0, 0);
    }
#pragma unroll
    for (int r = 0; r < 4; ++r) {
      const int o = o0 + wv * 16 + 4 * lq + r;
      const int head = o >> 5, dd = o & 31;
      const float a_[2] = {acc0[r], acc1[r]};
#pragma unroll
      for (int nf = 0; nf < 2; ++nf) {
        const int p = p0 + 16 * nf + lc;
        if (!isV) {
          k_lb[((size_t)(n * 8 + head) * PKV + p) * 32 + dd] =
              __float2bfloat16(a_[nf]);
        } else {
          v_t[((size_t)(n * 8 + head) * 32 + dd) * PKV + p] =
              __float2bfloat16(a_[nf]);
        }
      }
    }
  }
}

// ---------------------------------------------------------------------------
// EX table via MFMA (exy<0> body, output now bf16; EY is fused into attn).
// ---------------------------------------------------------------------------
__global__ __launch_bounds__(256) void ex_kernel(
    const __hip_bfloat16* __restrict__ qgb_b,
    const __hip_bfloat16* __restrict__ pembx_b,
    __hip_bfloat16* __restrict__ EX) {
  const int i = blockIdx.x;       // x
  const int g = blockIdx.y;
  const int head = g & 7;
  const int wv = threadIdx.x >> 6;
  const int l = threadIdx.x & 63;
  const int lc = l & 15, lq = l >> 4;

  const int rowi = wv * 16 + lc;  // y
  const int p = rowi * 64 + i;
  const short8 a = *reinterpret_cast<const short8*>(
      (const short*)qgb_b + ((size_t)g * PQ + p) * 32 + 8 * lq);

  const int drow0 = i - 2 * lc + 62;
  const int drow1 = i - 2 * (lc + 16) + 62;
  const short8 b0 = *reinterpret_cast<const short8*>(
      (const short*)pembx_b + (size_t)drow0 * 256 + head * 32 + 8 * lq);
  const short8 b1 = *reinterpret_cast<const short8*>(
      (const short*)pembx_b + (size_t)drow1 * 256 + head * 32 + 8 * lq);

  const f32x4 zero = {0.f, 0.f, 0.f, 0.f};
  const f32x4 c0 = __builtin_amdgcn_mfma_f32_16x16x32_bf16(a, b0, zero, 0, 0, 0);
  const f32x4 c1 = __builtin_amdgcn_mfma_f32_16x16x32_bf16(a, b1, zero, 0, 0, 0);

  const int lox = max((i - 16) >> 1, 0);
  const int hix = min(((i + 17) >> 1) + 1, 32);
#pragma unroll
  for (int r = 0; r < 4; ++r) {
    const int rowr = wv * 16 + 4 * lq + r;
    const int pr = rowr * 64 + i;
    __hip_bfloat16* o = EX + ((size_t)g * PQ + pr) * EXSTRIDE;
    o[lc] = __float2bfloat16(
        (lc >= lox && lc < hix) ? (c0[r] - M0) : -1e30f);
    o[16 + lc] = __float2bfloat16(
        (lc + 16 >= lox && lc + 16 < hix) ? (c1[r] - M0) : -1e30f);
    if (lc < 4) o[32 + lc] = __float2bfloat16(-1e30f);
  }
}

// ---------------------------------------------------------------------------
// MFMA local-window attention, 8-wave ky-parity split; EY computed IN-KERNEL
// (2 MFMAs per y-row by the s==0 waves, exy<1>'s exact operand formulas);
// EX read as bf16. Epilogue: fused att2b (R14-proven).
// ---------------------------------------------------------------------------
__global__ __launch_bounds__(512, 8) void attn_mfma_kernel(
    const __hip_bfloat16* __restrict__ qab_b,
    const __hip_bfloat16* __restrict__ qgb_b,
    const __hip_bfloat16* __restrict__ k_lb,
    const __hip_bfloat16* __restrict__ v_t,
    const __hip_bfloat16* __restrict__ EX,
    const __hip_bfloat16* __restrict__ pemby_b,
    __hip_bfloat16* __restrict__ attb) {
  const int g = blockIdx.y;    // n*8 + head
  const int nImg = g >> 3, hd = g & 7;
  const int bx = blockIdx.x & 3;   // x-tile of 16
  const int by = blockIdx.x >> 2;  // y-tile of 4 rows
  const int tx = bx * 16;
  const int wv = threadIdx.x >> 6;   // 0..7
  const int yw = wv & 3;             // y-row within tile
  const int s = wv >> 2;             // ky parity
  const int y = by * 4 + yw;
  const int l = threadIdx.x & 63;
  const int lc = l & 15;   // col lane (q for S^T / vd for O)
  const int lq = l >> 4;   // quarter

  __shared__ float eybuf[4][EYSTRIDE][16];  // [yrow][t][q]
  __shared__ float mrg[4][64][9];           // [yrow][lane][acc0*4,acc1*4,lp]
  __shared__ float obuf[4][16][33];         // [yrow][q][vd] fp32 O*inv

  const int KLO = max((tx - 16) >> 1, 0);
  const int lo_y = max((y - 16) >> 1, 0);
  const int hi_y = min(((y + 17) >> 1) + 1, 32);
  const int NKY = hi_y - lo_y;

  const int xq = tx + lc;
  const int pq_ = y * 64 + xq;

  // Qa B-frag: lane holds Qa[d=8lq+j][q=lc]
  const short8 qa = *reinterpret_cast<const short8*>(
      (const short*)qab_b + ((size_t)g * PQ + pq_) * 32 + 8 * lq);

  // per-lane loop-invariant ex registers (mask, M0, x-term baked; bf16 table)
  const short* exr = (const short*)EX + ((size_t)g * PQ + pq_) * EXSTRIDE;
  float exC0[4], exC1[4];
#pragma unroll
  for (int r = 0; r < 4; ++r) {
    exC0[r] = __bfloat162float(
        __builtin_bit_cast(__hip_bfloat16, exr[KLO + 4 * lq + r]));
    exC1[r] = __bfloat162float(
        __builtin_bit_cast(__hip_bfloat16, exr[min(KLO + 16 + 4 * lq + r, 35)]));
  }

  // ey computed in-kernel by s==0 waves: A-rows = this y-row's 16 pixels
  // (qgb frags), B-cols = ky slots (pemby rows, exy<1>'s drow formulas).
  // C: lane holds ey[q = 4lq+r][t = lc] -> eybuf[yw][t][q].
  if (s == 0) {
    const short8 ag = *reinterpret_cast<const short8*>(
        (const short*)qgb_b + ((size_t)g * PQ + pq_) * 32 + 8 * lq);
    const int dr0 = y - 2 * (lo_y + lc) + 62;
    const int dr1 = y - 2 * (lo_y + lc + 16) + 62;
    const short8 pb0 = *reinterpret_cast<const short8*>(
        (const short*)pemby_b + (size_t)dr0 * 256 + hd * 32 + 8 * lq);
    const short8 pb1 = *reinterpret_cast<const short8*>(
        (const short*)pemby_b + (size_t)dr1 * 256 + hd * 32 + 8 * lq);
    const f32x4 zero = {0.f, 0.f, 0.f, 0.f};
    const f32x4 e0 = __builtin_amdgcn_mfma_f32_16x16x32_bf16(ag, pb0, zero, 0, 0, 0);
    const f32x4 e1 = __builtin_amdgcn_mfma_f32_16x16x32_bf16(ag, pb1, zero, 0, 0, 0);
#pragma unroll
    for (int r = 0; r < 4; ++r) eybuf[yw][lc][4 * lq + r] = e0[r];
    if (lc < 4) {
#pragma unroll
      for (int r = 0; r < 4; ++r) eybuf[yw][16 + lc][4 * lq + r] = e1[r];
    }
  }
  __syncthreads();

  const __hip_bfloat16* kb =
      k_lb + ((size_t)g * PKV + (size_t)lo_y * 32) * 32;
  const __hip_bfloat16* kb0 = kb + (KLO + lc) * 32 + 8 * lq;
  const __hip_bfloat16* kb1 = kb + min(KLO + 16 + lc, 31) * 32 + 8 * lq;
  const __hip_bfloat16* vb0 =
      v_t + ((size_t)g * 32 + lc) * PKV + (size_t)lo_y * 32 + KLO + 8 * lq;
  const __hip_bfloat16* vb1 = vb0 + 16 * PKV;

  f32x4 acc0 = {0.f, 0.f, 0.f, 0.f};
  f32x4 acc1 = {0.f, 0.f, 0.f, 0.f};
  float lp = 0.f;
  const int srcA = lc + ((l & 16) << 1);  // lane lc + 32*(lq&1)
  const int srcB = srcA + 16;
  const bool hiL = (l & 32) != 0;

#pragma unroll 1
  for (int t = s; t < NKY; t += 2) {
    const short8 k0 = *reinterpret_cast<const short8*>(kb0 + t * 1024);
    const short8 k1 = *reinterpret_cast<const short8*>(kb1 + t * 1024);
    const short8 v0 = *reinterpret_cast<const short8*>(vb0 + t * 32);
    const short8 v1 = *reinterpret_cast<const short8*>(vb1 + t * 32);
    const f32x4 zero = {0.f, 0.f, 0.f, 0.f};
    // S^T tiles: rows kx_local = 4*lq + r, cols q = lc
    const f32x4 s0 = __builtin_amdgcn_mfma_f32_16x16x32_bf16(k0, qa, zero, 0, 0, 0);
    const f32x4 s1 = __builtin_amdgcn_mfma_f32_16x16x32_bf16(k1, qa, zero, 0, 0, 0);
    const float eyC = eybuf[yw][t][lc];
    float p0[4], p1[4];
#pragma unroll
    for (int r = 0; r < 4; ++r) {
      p0[r] = __expf(s0[r] + exC0[r] + eyC);   // masked: exC=-1e30 -> 0
      p1[r] = __expf(s1[r] + exC1[r] + eyC);
    }
    lp += ((p0[0] + p0[1]) + (p0[2] + p0[3])) +
          ((p1[0] + p1[1]) + (p1[2] + p1[3]));
    int w00, w01, w10, w11;
    asm("v_cvt_pk_bf16_f32 %0, %1, %2" : "=v"(w00) : "v"(p0[0]), "v"(p0[1]));
    asm("v_cvt_pk_bf16_f32 %0, %1, %2" : "=v"(w01) : "v"(p0[2]), "v"(p0[3]));
    asm("v_cvt_pk_bf16_f32 %0, %1, %2" : "=v"(w10) : "v"(p1[0]), "v"(p1[1]));
    asm("v_cvt_pk_bf16_f32 %0, %1, %2" : "=v"(w11) : "v"(p1[2]), "v"(p1[3]));
    const int a0 = __shfl(w00, srcA, 64), b0 = __shfl(w10, srcA, 64);
    const int a1 = __shfl(w01, srcA, 64), b1 = __shfl(w11, srcA, 64);
    const int a2 = __shfl(w00, srcB, 64), b2 = __shfl(w10, srcB, 64);
    const int a3 = __shfl(w01, srcB, 64), b3 = __shfl(w11, srcB, 64);
    int4 pw;
    pw.x = hiL ? b0 : a0;
    pw.y = hiL ? b1 : a1;
    pw.z = hiL ? b2 : a2;
    pw.w = hiL ? b3 : a3;
    const short8 pf = __builtin_bit_cast(short8, pw);
    acc0 = __builtin_amdgcn_mfma_f32_16x16x32_bf16(pf, v0, acc0, 0, 0, 0);
    acc1 = __builtin_amdgcn_mfma_f32_16x16x32_bf16(pf, v1, acc1, 0, 0, 0);
  }

  // pair-merge: parity-1 waves deposit (acc, lp); parity-0 waves add.
  if (s == 1) {
    float* m = mrg[yw][l];
#pragma unroll
    for (int r = 0; r < 4; ++r) m[r] = acc0[r];
#pragma unroll
    for (int r = 0; r < 4; ++r) m[4 + r] = acc1[r];
    m[8] = lp;
  }
  __syncthreads();
  if (s == 1) return;
  {
    const float* m = mrg[yw][l];
#pragma unroll
    for (int r = 0; r < 4; ++r) acc0[r] += m[r];
#pragma unroll
    for (int r = 0; r < 4; ++r) acc1[r] += m[4 + r];
    lp += m[8];
  }

  // l: sum over the 4 lq groups -> every lane holds L[q=lc]
  lp += __shfl_xor(lp, 16);
  lp += __shfl_xor(lp, 32);
  const float invall = 1.f / lp;

  // fused att2b epilogue: O*inv -> obuf (wave-private yw slice) -> bf16 attb
#pragma unroll
  for (int r = 0; r < 4; ++r) {
    const float inv = __shfl(invall, 4 * lq + r, 16);  // L for q = 4lq+r
    obuf[yw][4 * lq + r][lc] = acc0[r] * inv;
    obuf[yw][4 * lq + r][16 + lc] = acc1[r] * inv;
  }
  const int qp = l >> 2;
  const int ch = (l & 3) * 8;
  short8 sv;
#pragma unroll
  for (int j = 0; j < 8; ++j)
    sv[j] = __builtin_bit_cast(short, __float2bfloat16(obuf[yw][qp][ch + j]));
  const int p = y * 64 + tx + qp;
  *reinterpret_cast<short8*>(
      (short*)attb + ((size_t)nImg * PQ + p) * 256 + hd * 32 + ch) = sv;
}

// ---------------------------------------------------------------------------
// MFMA GEMM: output projection + bias + gamma + residual (R14-proven).
// ---------------------------------------------------------------------------
__global__ __launch_bounds__(256) void gemm_out_kernel(
    const __hip_bfloat16* __restrict__ attb,
    const __hip_bfloat16* __restrict__ pw, const float* __restrict__ pb,
    const float* __restrict__ gamma, const float* __restrict__ x_in,
    float* __restrict__ out) {
  const int p0 = blockIdx.x * 32;
  const int o0 = blockIdx.y * 64;
  const int n = blockIdx.z;
  const int tid = threadIdx.x;
  const int wv = tid >> 6, l = tid & 63, lc = l & 15, lq = l >> 4;
  const short* ar =
      (const short*)pw + ((size_t)(o0 + wv * 16 + lc)) * 256 + 8 * lq;
  const short* bbase = (const short*)attb + ((size_t)n * PQ + p0) * 256 + 8 * lq;
  const short* b0p = bbase + (size_t)(0 + lc) * 256;
  const short* b1p = bbase + (size_t)(16 + lc) * 256;
  f32x4 acc0 = {0.f, 0.f, 0.f, 0.f};
  f32x4 acc1 = {0.f, 0.f, 0.f, 0.f};
#pragma unroll
  for (int kt = 0; kt < 8; ++kt) {
    const short8 af = *reinterpret_cast<const short8*>(ar + kt * 32);
    acc0 = __builtin_amdgcn_mfma_f32_16x16x32_bf16(
        af, *reinterpret_cast<const short8*>(b0p + kt * 32), acc0, 0, 0, 0);
    acc1 = __builtin_amdgcn_mfma_f32_16x16x32_bf16(
        af, *reinterpret_cast<const short8*>(b1p + kt * 32), acc1, 0, 0, 0);
  }
  const float gm = gamma[0];
#pragma unroll
  for (int r = 0; r < 4; ++r) {
    const int o = o0 + wv * 16 + 4 * lq + r;   // C row = 4*lq + r
    const float bo = pb[o];
    const size_t obase = ((size_t)n * 256 + o) * PQ;
    const size_t i0 = obase + (p0 + 0 + lc);
    const size_t i1 = obase + (p0 + 16 + lc);
    out[i0] = fmaf(gm, acc0[r] + bo, x_in[i0]);
    out[i1] = fmaf(gm, acc1[r] + bo, x_in[i1]);
  }
}

// ---------------------------------------------------------------------------
extern "C" void kernel_launch(void* const* d_in, const int* in_sizes, int n_in,
                              void* d_out, int out_size, void* d_ws,
                              size_t ws_size, hipStream_t stream) {
  const float* x = (const float*)d_in[0];
  const float* q_w = (const float*)d_in[1];
  const float* k_w = (const float*)d_in[2];
  const float* v_w = (const float*)d_in[3];
  const float* fcx_w = (const float*)d_in[4];
  const float* fcy_w = (const float*)d_in[5];
  const float* ab = (const float*)d_in[6];
  const float* gb = (const float*)d_in[7];
  const float* proj_w = (const float*)d_in[8];
  const float* proj_b = (const float*)d_in[9];
  const float* gamma = (const float*)d_in[10];
  float* out = (float*)d_out;

  __hip_bfloat16* bp = (__hip_bfloat16*)d_ws;
  __hip_bfloat16* EX = bp;      bp += 2359296;   // 16*4096*36 bf16
  __hip_bfloat16* qab_b = bp;   bp += 2097152;
  __hip_bfloat16* qgb_b = bp;   bp += 2097152;
  __hip_bfloat16* k_lb = bp;    bp += 524288;
  __hip_bfloat16* v_t = bp;     bp += 524288;
  __hip_bfloat16* pembx_b = bp; bp += 32256;
  __hip_bfloat16* pemby_b = bp; bp += 32256;
  __hip_bfloat16* qw_b = bp;    bp += 65536;
  __hip_bfloat16* kw_b = bp;    bp += 65536;
  __hip_bfloat16* vw_b = bp;    bp += 65536;
  __hip_bfloat16* pw_b = bp;    bp += 65536;
  __hip_bfloat16* xb = bp;      bp += 2097152;
  __hip_bfloat16* attb = bp;    bp += 2097152;
  // total = 12,123,136 bf16 = 24.2 MB

  prep_kernel<<<dim3(1020), 256, 0, stream>>>(q_w, k_w, v_w, proj_w, qw_b,
                                              kw_b, vw_b, pw_b, fcx_w, fcy_w,
                                              pembx_b, pemby_b, x, xb);
  gemm_qkv_kernel<<<dim3(1536), 256, 0, stream>>>(xb, qw_b, kw_b, vw_b, ab,
                                                  gb, qab_b, qgb_b, k_lb, v_t);
  ex_kernel<<<dim3(64, 16), 256, 0, stream>>>(qgb_b, pembx_b, EX);
  attn_mfma_kernel<<<dim3(64, 16), 512, 0, stream>>>(qab_b, qgb_b, k_lb, v_t,
                                                     EX, pemby_b, attb);
  gemm_out_kernel<<<dim3(128, 4, 2), 256, 0, stream>>>(attb, pw_b, proj_b,
                                                       gamma, x, out);
}

// Round 17
// 75.889 us; speedup vs baseline: 1.3348x; 1.1339x over previous
//
#include <hip/hip_runtime.h>
#include <hip/hip_bf16.h>
#include <math.h>

// Problem sizes (fixed by the reference)
#define NB   2
#define CC   256
#define PQ   4096   // 64*64 queries per image
#define PKV  1024   // 32*32 kv per image

#define M0 24.0f    // fixed softmax offset (baked into EX; |e| << 80)
#define EXSTRIDE 36
#define EYSTRIDE 20

typedef __attribute__((ext_vector_type(8))) short short8;
typedef __attribute__((ext_vector_type(4))) float f32x4;

// ---------------------------------------------------------------------------
// Fused prep: blocks 0..255 weights fp32->bf16; 256..507 posfeat pemb tables;
// 508..1019 x transpose to bf16 pixel-major xb[n][p][c]. (R15-proven)
// ---------------------------------------------------------------------------
__global__ __launch_bounds__(256) void prep_kernel(
    const float* __restrict__ q_w, const float* __restrict__ k_w,
    const float* __restrict__ v_w, const float* __restrict__ proj_w,
    __hip_bfloat16* __restrict__ qw_b, __hip_bfloat16* __restrict__ kw_b,
    __hip_bfloat16* __restrict__ vw_b, __hip_bfloat16* __restrict__ pw_b,
    const float* __restrict__ fcx, const float* __restrict__ fcy,
    __hip_bfloat16* __restrict__ pembx_b, __hip_bfloat16* __restrict__ pemby_b,
    const float* __restrict__ x, __hip_bfloat16* __restrict__ xb) {
  __shared__ __align__(16) float shbuf[64 * 65];
  const int bid = blockIdx.x;
  const int tid = threadIdx.x;
  if (bid < 256) {
    const int which = bid >> 6;
    const float* src = (which == 0) ? q_w : (which == 1) ? k_w
                       : (which == 2) ? v_w : proj_w;
    __hip_bfloat16* dst = (which == 0) ? qw_b : (which == 1) ? kw_b
                          : (which == 2) ? vw_b : pw_b;
    const int i = (bid & 63) * 256 + tid;
    const float4 v = reinterpret_cast<const float4*>(src)[i];
    short4 s;
    s.x = __builtin_bit_cast(short, __float2bfloat16(v.x));
    s.y = __builtin_bit_cast(short, __float2bfloat16(v.y));
    s.z = __builtin_bit_cast(short, __float2bfloat16(v.z));
    s.w = __builtin_bit_cast(short, __float2bfloat16(v.w));
    reinterpret_cast<short4*>(dst)[i] = s;
  } else if (bid < 508) {
    float* feat = shbuf;
    const int pb = bid - 256;        // 0..251
    const int dd = pb >> 1;          // 0..125 -> diff = dd - 62
    const int which = pb & 1;
    const float* FC = which ? fcy : fcx;
    __hip_bfloat16* OUT = which ? pemby_b : pembx_b;
    if (tid < 64) {
      const float diff = (float)(dd - 62);
      const float dm = powf(1000.f, (float)tid * (1.f / 64.f));
      const float aa = diff / dm;
      feat[tid] = sinf(aa);
      feat[tid + 64] = cosf(aa);
    }
    __syncthreads();
    const float4* row4 = reinterpret_cast<const float4*>(FC + tid * 128);
    const float4* f4 = reinterpret_cast<const float4*>(feat);
    float s0 = 0.f, s1 = 0.f, s2 = 0.f, s3 = 0.f;
#pragma unroll
    for (int f = 0; f < 32; ++f) {
      const float4 fv = f4[f];
      const float4 rv = row4[f];
      s0 = fmaf(fv.x, rv.x, s0);
      s1 = fmaf(fv.y, rv.y, s1);
      s2 = fmaf(fv.z, rv.z, s2);
      s3 = fmaf(fv.w, rv.w, s3);
    }
    const float s = ((s0 + s1) + (s2 + s3)) * 0.70710678118654752440f;
    OUT[(size_t)dd * 256 + tid] = __float2bfloat16(s);
  } else {
    float (*t)[65] = reinterpret_cast<float(*)[65]>(shbuf);
    const int b = bid - 508;
    const int p0 = (b & 63) * 64;
    const int c0 = ((b >> 6) & 3) * 64;
    const int n = b >> 8;
    {
      const int pl = tid & 63, cg = tid >> 6;
#pragma unroll
      for (int i = 0; i < 16; ++i) {
        const int cl = cg * 16 + i;
        t[cl][pl] = x[((size_t)n * 256 + c0 + cl) * PQ + p0 + pl];
      }
    }
    __syncthreads();
    const int cl = tid & 63;
#pragma unroll
    for (int j = 0; j < 16; ++j) {
      const int pl = (tid >> 6) + 4 * j;
      ((__hip_bfloat16*)xb)[((size_t)n * PQ + p0 + pl) * 256 + c0 + cl] =
          __float2bfloat16(t[cl][pl]);
    }
  }
}

// ---------------------------------------------------------------------------
// Fused Q + K/V projection GEMMs. B-tile (32 pixels x 256 c) now staged in
// LDS via coalesced 16B loads with XOR-swizzled chunk placement (T2): the
// former per-lane stride-512B B-frag gathers (≈64 L1 lines/instr) become
// bank-balanced LDS reads. Math bit-identical to R15.
// ---------------------------------------------------------------------------
__global__ __launch_bounds__(256) void gemm_qkv_kernel(
    const __hip_bfloat16* __restrict__ xb,
    const __hip_bfloat16* __restrict__ qw, const __hip_bfloat16* __restrict__ kw,
    const __hip_bfloat16* __restrict__ vw, const float* __restrict__ ab,
    const float* __restrict__ gb, __hip_bfloat16* __restrict__ qab,
    __hip_bfloat16* __restrict__ qgb, __hip_bfloat16* __restrict__ k_lb,
    __hip_bfloat16* __restrict__ v_t) {
  __shared__ short bt[32 * 256];   // 16 KB, XOR-swizzled 16B chunks
  const int bid = blockIdx.x;
  const int tid = threadIdx.x;
  const int wv = tid >> 6, l = tid & 63, lc = l & 15, lq = l >> 4;

  const bool isQ = (bid < 1024);
  int n, o0, p0;
  bool isV = false;
  const __hip_bfloat16* W;
  if (isQ) {
    n = bid & 1;
    o0 = ((bid >> 1) & 3) * 64;
    p0 = (bid >> 3) * 32;
    W = qw;
  } else {
    const int kb2 = bid - 1024;
    n = kb2 & 1;
    o0 = ((kb2 >> 1) & 3) * 64;
    isV = ((kb2 >> 3) & 1) != 0;
    p0 = (kb2 >> 4) * 32;
    W = isV ? vw : kw;
  }

  // stage B tile: row = pixel index within tile, 256 channels each
  {
    const int row = tid >> 3;            // 0..31
    const int pk = p0 + row;
    const int gp = isQ ? pk : ((pk >> 5) * 128 + (pk & 31) * 2);
    const short* src = (const short*)xb + ((size_t)n * PQ + gp) * 256;
#pragma unroll
    for (int j = 0; j < 4; ++j) {
      const int chunk = (tid & 7) + 8 * j;   // 16B chunk index 0..31
      const int4 v = *reinterpret_cast<const int4*>(src + chunk * 8);
      *reinterpret_cast<int4*>(bt + row * 256 + ((chunk ^ (row & 7)) << 3)) = v;
    }
  }
  __syncthreads();

  const short* ar =
      (const short*)W + ((size_t)(o0 + wv * 16 + lc)) * 256 + 8 * lq;
  f32x4 acc0 = {0.f, 0.f, 0.f, 0.f};
  f32x4 acc1 = {0.f, 0.f, 0.f, 0.f};
#pragma unroll
  for (int kt = 0; kt < 8; ++kt) {
    const short8 af = *reinterpret_cast<const short8*>(ar + kt * 32);
    const int c0i = lq + 4 * kt;           // chunk col for shorts 8lq+32kt
    const short8 bf0 = *reinterpret_cast<const short8*>(
        bt + lc * 256 + ((c0i ^ (lc & 7)) << 3));
    const short8 bf1 = *reinterpret_cast<const short8*>(
        bt + (16 + lc) * 256 + ((c0i ^ ((16 + lc) & 7)) << 3));
    acc0 = __builtin_amdgcn_mfma_f32_16x16x32_bf16(af, bf0, acc0, 0, 0, 0);
    acc1 = __builtin_amdgcn_mfma_f32_16x16x32_bf16(af, bf1, acc1, 0, 0, 0);
  }

  if (isQ) {
#pragma unroll
    for (int r = 0; r < 4; ++r) {
      const int o = o0 + wv * 16 + 4 * lq + r;
      const float abo = ab[o], gbo = gb[o];
      const int head = o >> 5, dd = o & 31;
      const size_t gbase = (size_t)(n * 8 + head) * PQ;
      const float a_[2] = {acc0[r], acc1[r]};
#pragma unroll
      for (int nf = 0; nf < 2; ++nf) {
        const int p = p0 + 16 * nf + lc;
        const size_t idx = (gbase + p) * 32 + dd;
        qab[idx] = __float2bfloat16(a_[nf] + abo);
        qgb[idx] = __float2bfloat16(a_[nf] + gbo);
      }
    }
  } else {
#pragma unroll
    for (int r = 0; r < 4; ++r) {
      const int o = o0 + wv * 16 + 4 * lq + r;
      const int head = o >> 5, dd = o & 31;
      const float a_[2] = {acc0[r], acc1[r]};
#pragma unroll
      for (int nf = 0; nf < 2; ++nf) {
        const int p = p0 + 16 * nf + lc;
        if (!isV) {
          k_lb[((size_t)(n * 8 + head) * PKV + p) * 32 + dd] =
              __float2bfloat16(a_[nf]);
        } else {
          v_t[((size_t)(n * 8 + head) * 32 + dd) * PKV + p] =
              __float2bfloat16(a_[nf]);
        }
      }
    }
  }
}

// ---------------------------------------------------------------------------
// EX table via MFMA (R15-proven, unchanged; bf16 output).
// ---------------------------------------------------------------------------
__global__ __launch_bounds__(256) void ex_kernel(
    const __hip_bfloat16* __restrict__ qgb_b,
    const __hip_bfloat16* __restrict__ pembx_b,
    __hip_bfloat16* __restrict__ EX) {
  const int i = blockIdx.x;       // x
  const int g = blockIdx.y;
  const int head = g & 7;
  const int wv = threadIdx.x >> 6;
  const int l = threadIdx.x & 63;
  const int lc = l & 15, lq = l >> 4;

  const int rowi = wv * 16 + lc;  // y
  const int p = rowi * 64 + i;
  const short8 a = *reinterpret_cast<const short8*>(
      (const short*)qgb_b + ((size_t)g * PQ + p) * 32 + 8 * lq);

  const int drow0 = i - 2 * lc + 62;
  const int drow1 = i - 2 * (lc + 16) + 62;
  const short8 b0 = *reinterpret_cast<const short8*>(
      (const short*)pembx_b + (size_t)drow0 * 256 + head * 32 + 8 * lq);
  const short8 b1 = *reinterpret_cast<const short8*>(
      (const short*)pembx_b + (size_t)drow1 * 256 + head * 32 + 8 * lq);

  const f32x4 zero = {0.f, 0.f, 0.f, 0.f};
  const f32x4 c0 = __builtin_amdgcn_mfma_f32_16x16x32_bf16(a, b0, zero, 0, 0, 0);
  const f32x4 c1 = __builtin_amdgcn_mfma_f32_16x16x32_bf16(a, b1, zero, 0, 0, 0);

  const int lox = max((i - 16) >> 1, 0);
  const int hix = min(((i + 17) >> 1) + 1, 32);
#pragma unroll
  for (int r = 0; r < 4; ++r) {
    const int rowr = wv * 16 + 4 * lq + r;
    const int pr = rowr * 64 + i;
    __hip_bfloat16* o = EX + ((size_t)g * PQ + pr) * EXSTRIDE;
    o[lc] = __float2bfloat16(
        (lc >= lox && lc < hix) ? (c0[r] - M0) : -1e30f);
    o[16 + lc] = __float2bfloat16(
        (lc + 16 >= lox && lc + 16 < hix) ? (c1[r] - M0) : -1e30f);
    if (lc < 4) o[32 + lc] = __float2bfloat16(-1e30f);
  }
}

// ---------------------------------------------------------------------------
// MFMA local-window attention (R15-proven, unchanged): 8-wave ky-parity
// split, in-kernel EY, bf16 EX, fused att2b epilogue.
// ---------------------------------------------------------------------------
__global__ __launch_bounds__(512, 8) void attn_mfma_kernel(
    const __hip_bfloat16* __restrict__ qab_b,
    const __hip_bfloat16* __restrict__ qgb_b,
    const __hip_bfloat16* __restrict__ k_lb,
    const __hip_bfloat16* __restrict__ v_t,
    const __hip_bfloat16* __restrict__ EX,
    const __hip_bfloat16* __restrict__ pemby_b,
    __hip_bfloat16* __restrict__ attb) {
  const int g = blockIdx.y;    // n*8 + head
  const int nImg = g >> 3, hd = g & 7;
  const int bx = blockIdx.x & 3;   // x-tile of 16
  const int by = blockIdx.x >> 2;  // y-tile of 4 rows
  const int tx = bx * 16;
  const int wv = threadIdx.x >> 6;   // 0..7
  const int yw = wv & 3;             // y-row within tile
  const int s = wv >> 2;             // ky parity
  const int y = by * 4 + yw;
  const int l = threadIdx.x & 63;
  const int lc = l & 15;   // col lane (q for S^T / vd for O)
  const int lq = l >> 4;   // quarter

  __shared__ float eybuf[4][EYSTRIDE][16];  // [yrow][t][q]
  __shared__ float mrg[4][64][9];           // [yrow][lane][acc0*4,acc1*4,lp]
  __shared__ float obuf[4][16][33];         // [yrow][q][vd] fp32 O*inv

  const int KLO = max((tx - 16) >> 1, 0);
  const int lo_y = max((y - 16) >> 1, 0);
  const int hi_y = min(((y + 17) >> 1) + 1, 32);
  const int NKY = hi_y - lo_y;

  const int xq = tx + lc;
  const int pq_ = y * 64 + xq;

  // Qa B-frag: lane holds Qa[d=8lq+j][q=lc]
  const short8 qa = *reinterpret_cast<const short8*>(
      (const short*)qab_b + ((size_t)g * PQ + pq_) * 32 + 8 * lq);

  // per-lane loop-invariant ex registers (mask, M0, x-term baked; bf16 table)
  const short* exr = (const short*)EX + ((size_t)g * PQ + pq_) * EXSTRIDE;
  float exC0[4], exC1[4];
#pragma unroll
  for (int r = 0; r < 4; ++r) {
    exC0[r] = __bfloat162float(
        __builtin_bit_cast(__hip_bfloat16, exr[KLO + 4 * lq + r]));
    exC1[r] = __bfloat162float(
        __builtin_bit_cast(__hip_bfloat16, exr[min(KLO + 16 + 4 * lq + r, 35)]));
  }

  // ey computed in-kernel by s==0 waves (exy<1>'s exact operand formulas)
  if (s == 0) {
    const short8 ag = *reinterpret_cast<const short8*>(
        (const short*)qgb_b + ((size_t)g * PQ + pq_) * 32 + 8 * lq);
    const int dr0 = y - 2 * (lo_y + lc) + 62;
    const int dr1 = y - 2 * (lo_y + lc + 16) + 62;
    const short8 pb0 = *reinterpret_cast<const short8*>(
        (const short*)pemby_b + (size_t)dr0 * 256 + hd * 32 + 8 * lq);
    const short8 pb1 = *reinterpret_cast<const short8*>(
        (const short*)pemby_b + (size_t)dr1 * 256 + hd * 32 + 8 * lq);
    const f32x4 zero = {0.f, 0.f, 0.f, 0.f};
    const f32x4 e0 = __builtin_amdgcn_mfma_f32_16x16x32_bf16(ag, pb0, zero, 0, 0, 0);
    const f32x4 e1 = __builtin_amdgcn_mfma_f32_16x16x32_bf16(ag, pb1, zero, 0, 0, 0);
#pragma unroll
    for (int r = 0; r < 4; ++r) eybuf[yw][lc][4 * lq + r] = e0[r];
    if (lc < 4) {
#pragma unroll
      for (int r = 0; r < 4; ++r) eybuf[yw][16 + lc][4 * lq + r] = e1[r];
    }
  }
  __syncthreads();

  const __hip_bfloat16* kb =
      k_lb + ((size_t)g * PKV + (size_t)lo_y * 32) * 32;
  const __hip_bfloat16* kb0 = kb + (KLO + lc) * 32 + 8 * lq;
  const __hip_bfloat16* kb1 = kb + min(KLO + 16 + lc, 31) * 32 + 8 * lq;
  const __hip_bfloat16* vb0 =
      v_t + ((size_t)g * 32 + lc) * PKV + (size_t)lo_y * 32 + KLO + 8 * lq;
  const __hip_bfloat16* vb1 = vb0 + 16 * PKV;

  f32x4 acc0 = {0.f, 0.f, 0.f, 0.f};
  f32x4 acc1 = {0.f, 0.f, 0.f, 0.f};
  float lp = 0.f;
  const int srcA = lc + ((l & 16) << 1);  // lane lc + 32*(lq&1)
  const int srcB = srcA + 16;
  const bool hiL = (l & 32) != 0;

#pragma unroll 1
  for (int t = s; t < NKY; t += 2) {
    const short8 k0 = *reinterpret_cast<const short8*>(kb0 + t * 1024);
    const short8 k1 = *reinterpret_cast<const short8*>(kb1 + t * 1024);
    const short8 v0 = *reinterpret_cast<const short8*>(vb0 + t * 32);
    const short8 v1 = *reinterpret_cast<const short8*>(vb1 + t * 32);
    const f32x4 zero = {0.f, 0.f, 0.f, 0.f};
    // S^T tiles: rows kx_local = 4*lq + r, cols q = lc
    const f32x4 s0 = __builtin_amdgcn_mfma_f32_16x16x32_bf16(k0, qa, zero, 0, 0, 0);
    const f32x4 s1 = __builtin_amdgcn_mfma_f32_16x16x32_bf16(k1, qa, zero, 0, 0, 0);
    const float eyC = eybuf[yw][t][lc];
    float p0[4], p1[4];
#pragma unroll
    for (int r = 0; r < 4; ++r) {
      p0[r] = __expf(s0[r] + exC0[r] + eyC);   // masked: exC=-1e30 -> 0
      p1[r] = __expf(s1[r] + exC1[r] + eyC);
    }
    lp += ((p0[0] + p0[1]) + (p0[2] + p0[3])) +
          ((p1[0] + p1[1]) + (p1[2] + p1[3]));
    int w00, w01, w10, w11;
    asm("v_cvt_pk_bf16_f32 %0, %1, %2" : "=v"(w00) : "v"(p0[0]), "v"(p0[1]));
    asm("v_cvt_pk_bf16_f32 %0, %1, %2" : "=v"(w01) : "v"(p0[2]), "v"(p0[3]));
    asm("v_cvt_pk_bf16_f32 %0, %1, %2" : "=v"(w10) : "v"(p1[0]), "v"(p1[1]));
    asm("v_cvt_pk_bf16_f32 %0, %1, %2" : "=v"(w11) : "v"(p1[2]), "v"(p1[3]));
    const int a0 = __shfl(w00, srcA, 64), b0 = __shfl(w10, srcA, 64);
    const int a1 = __shfl(w01, srcA, 64), b1 = __shfl(w11, srcA, 64);
    const int a2 = __shfl(w00, srcB, 64), b2 = __shfl(w10, srcB, 64);
    const int a3 = __shfl(w01, srcB, 64), b3 = __shfl(w11, srcB, 64);
    int4 pw;
    pw.x = hiL ? b0 : a0;
    pw.y = hiL ? b1 : a1;
    pw.z = hiL ? b2 : a2;
    pw.w = hiL ? b3 : a3;
    const short8 pf = __builtin_bit_cast(short8, pw);
    acc0 = __builtin_amdgcn_mfma_f32_16x16x32_bf16(pf, v0, acc0, 0, 0, 0);
    acc1 = __builtin_amdgcn_mfma_f32_16x16x32_bf16(pf, v1, acc1, 0, 0, 0);
  }

  // pair-merge: parity-1 waves deposit (acc, lp); parity-0 waves add.
  if (s == 1) {
    float* m = mrg[yw][l];
#pragma unroll
    for (int r = 0; r < 4; ++r) m[r] = acc0[r];
#pragma unroll
    for (int r = 0; r < 4; ++r) m[4 + r] = acc1[r];
    m[8] = lp;
  }
  __syncthreads();
  if (s == 1) return;
  {
    const float* m = mrg[yw][l];
#pragma unroll
    for (int r = 0; r < 4; ++r) acc0[r] += m[r];
#pragma unroll
    for (int r = 0; r < 4; ++r) acc1[r] += m[4 + r];
    lp += m[8];
  }

  // l: sum over the 4 lq groups -> every lane holds L[q=lc]
  lp += __shfl_xor(lp, 16);
  lp += __shfl_xor(lp, 32);
  const float invall = 1.f / lp;

  // fused att2b epilogue: O*inv -> obuf (wave-private yw slice) -> bf16 attb
#pragma unroll
  for (int r = 0; r < 4; ++r) {
    const float inv = __shfl(invall, 4 * lq + r, 16);  // L for q = 4lq+r
    obuf[yw][4 * lq + r][lc] = acc0[r] * inv;
    obuf[yw][4 * lq + r][16 + lc] = acc1[r] * inv;
  }
  const int qp = l >> 2;
  const int ch = (l & 3) * 8;
  short8 sv;
#pragma unroll
  for (int j = 0; j < 8; ++j)
    sv[j] = __builtin_bit_cast(short, __float2bfloat16(obuf[yw][qp][ch + j]));
  const int p = y * 64 + tx + qp;
  *reinterpret_cast<short8*>(
      (short*)attb + ((size_t)nImg * PQ + p) * 256 + hd * 32 + ch) = sv;
}

// ---------------------------------------------------------------------------
// MFMA GEMM: output projection + bias + gamma + residual. B-tile (attb)
// staged in LDS with the same XOR-swizzle as gemm_qkv. Math identical.
// ---------------------------------------------------------------------------
__global__ __launch_bounds__(256) void gemm_out_kernel(
    const __hip_bfloat16* __restrict__ attb,
    const __hip_bfloat16* __restrict__ pw, const float* __restrict__ pb,
    const float* __restrict__ gamma, const float* __restrict__ x_in,
    float* __restrict__ out) {
  __shared__ short bt[32 * 256];   // 16 KB
  const int p0 = blockIdx.x * 32;
  const int o0 = blockIdx.y * 64;
  const int n = blockIdx.z;
  const int tid = threadIdx.x;
  const int wv = tid >> 6, l = tid & 63, lc = l & 15, lq = l >> 4;

  // stage B tile (32 pixels x 256 c), coalesced + XOR-swizzled chunks
  {
    const int row = tid >> 3;
    const short* src = (const short*)attb + ((size_t)n * PQ + p0 + row) * 256;
#pragma unroll
    for (int j = 0; j < 4; ++j) {
      const int chunk = (tid & 7) + 8 * j;
      const int4 v = *reinterpret_cast<const int4*>(src + chunk * 8);
      *reinterpret_cast<int4*>(bt + row * 256 + ((chunk ^ (row & 7)) << 3)) = v;
    }
  }
  __syncthreads();

  const short* ar =
      (const short*)pw + ((size_t)(o0 + wv * 16 + lc)) * 256 + 8 * lq;
  f32x4 acc0 = {0.f, 0.f, 0.f, 0.f};
  f32x4 acc1 = {0.f, 0.f, 0.f, 0.f};
#pragma unroll
  for (int kt = 0; kt < 8; ++kt) {
    const short8 af = *reinterpret_cast<const short8*>(ar + kt * 32);
    const int c0i = lq + 4 * kt;
    const short8 bf0 = *reinterpret_cast<const short8*>(
        bt + lc * 256 + ((c0i ^ (lc & 7)) << 3));
    const short8 bf1 = *reinterpret_cast<const short8*>(
        bt + (16 + lc) * 256 + ((c0i ^ ((16 + lc) & 7)) << 3));
    acc0 = __builtin_amdgcn_mfma_f32_16x16x32_bf16(af, bf0, acc0, 0, 0, 0);
    acc1 = __builtin_amdgcn_mfma_f32_16x16x32_bf16(af, bf1, acc1, 0, 0, 0);
  }
  const float gm = gamma[0];
#pragma unroll
  for (int r = 0; r < 4; ++r) {
    const int o = o0 + wv * 16 + 4 * lq + r;   // C row = 4*lq + r
    const float bo = pb[o];
    const size_t obase = ((size_t)n * 256 + o) * PQ;
    const size_t i0 = obase + (p0 + 0 + lc);
    const size_t i1 = obase + (p0 + 16 + lc);
    out[i0] = fmaf(gm, acc0[r] + bo, x_in[i0]);
    out[i1] = fmaf(gm, acc1[r] + bo, x_in[i1]);
  }
}

// ---------------------------------------------------------------------------
extern "C" void kernel_launch(void* const* d_in, const int* in_sizes, int n_in,
                              void* d_out, int out_size, void* d_ws,
                              size_t ws_size, hipStream_t stream) {
  const float* x = (const float*)d_in[0];
  const float* q_w = (const float*)d_in[1];
  const float* k_w = (const float*)d_in[2];
  const float* v_w = (const float*)d_in[3];
  const float* fcx_w = (const float*)d_in[4];
  const float* fcy_w = (const float*)d_in[5];
  const float* ab = (const float*)d_in[6];
  const float* gb = (const float*)d_in[7];
  const float* proj_w = (const float*)d_in[8];
  const float* proj_b = (const float*)d_in[9];
  const float* gamma = (const float*)d_in[10];
  float* out = (float*)d_out;

  __hip_bfloat16* bp = (__hip_bfloat16*)d_ws;
  __hip_bfloat16* EX = bp;      bp += 2359296;   // 16*4096*36 bf16
  __hip_bfloat16* qab_b = bp;   bp += 2097152;
  __hip_bfloat16* qgb_b = bp;   bp += 2097152;
  __hip_bfloat16* k_lb = bp;    bp += 524288;
  __hip_bfloat16* v_t = bp;     bp += 524288;
  __hip_bfloat16* pembx_b = bp; bp += 32256;
  __hip_bfloat16* pemby_b = bp; bp += 32256;
  __hip_bfloat16* qw_b = bp;    bp += 65536;
  __hip_bfloat16* kw_b = bp;    bp += 65536;
  __hip_bfloat16* vw_b = bp;    bp += 65536;
  __hip_bfloat16* pw_b = bp;    bp += 65536;
  __hip_bfloat16* xb = bp;      bp += 2097152;
  __hip_bfloat16* attb = bp;    bp += 2097152;
  // total = 12,123,136 bf16 = 24.2 MB

  prep_kernel<<<dim3(1020), 256, 0, stream>>>(q_w, k_w, v_w, proj_w, qw_b,
                                              kw_b, vw_b, pw_b, fcx_w, fcy_w,
                                              pembx_b, pemby_b, x, xb);
  gemm_qkv_kernel<<<dim3(1536), 256, 0, stream>>>(xb, qw_b, kw_b, vw_b, ab,
                                                  gb, qab_b, qgb_b, k_lb, v_t);
  ex_kernel<<<dim3(64, 16), 256, 0, stream>>>(qgb_b, pembx_b, EX);
  attn_mfma_kernel<<<dim3(64, 16), 512, 0, stream>>>(qab_b, qgb_b, k_lb, v_t,
                                                     EX, pemby_b, attb);
  gemm_out_kernel<<<dim3(128, 4, 2), 256, 0, stream>>>(attb, pw_b, proj_b,
                                                       gamma, x, out);
}

// Round 19
// 74.928 us; speedup vs baseline: 1.3519x; 1.0128x over previous
//
#include <hip/hip_runtime.h>
#include <hip/hip_bf16.h>
#include <math.h>

// Problem sizes (fixed by the reference)
#define NB   2
#define CC   256
#define PQ   4096   // 64*64 queries per image
#define PKV  1024   // 32*32 kv per image

#define M0 24.0f    // fixed softmax offset (baked into EX; |e| << 80)
#define EXSTRIDE 36
#define EYSTRIDE 20

typedef __attribute__((ext_vector_type(8))) short short8;
typedef __attribute__((ext_vector_type(4))) float f32x4;

// ---------------------------------------------------------------------------
// Fused prep: blocks 0..255 weights fp32->bf16; 256..507 posfeat pemb tables;
// 508..1019 x transpose to bf16 pixel-major xb[n][p][c]. (R17-proven)
// ---------------------------------------------------------------------------
__global__ __launch_bounds__(256) void prep_kernel(
    const float* __restrict__ q_w, const float* __restrict__ k_w,
    const float* __restrict__ v_w, const float* __restrict__ proj_w,
    __hip_bfloat16* __restrict__ qw_b, __hip_bfloat16* __restrict__ kw_b,
    __hip_bfloat16* __restrict__ vw_b, __hip_bfloat16* __restrict__ pw_b,
    const float* __restrict__ fcx, const float* __restrict__ fcy,
    __hip_bfloat16* __restrict__ pembx_b, __hip_bfloat16* __restrict__ pemby_b,
    const float* __restrict__ x, __hip_bfloat16* __restrict__ xb) {
  __shared__ __align__(16) float shbuf[64 * 65];
  const int bid = blockIdx.x;
  const int tid = threadIdx.x;
  if (bid < 256) {
    const int which = bid >> 6;
    const float* src = (which == 0) ? q_w : (which == 1) ? k_w
                       : (which == 2) ? v_w : proj_w;
    __hip_bfloat16* dst = (which == 0) ? qw_b : (which == 1) ? kw_b
                          : (which == 2) ? vw_b : pw_b;
    const int i = (bid & 63) * 256 + tid;
    const float4 v = reinterpret_cast<const float4*>(src)[i];
    short4 s;
    s.x = __builtin_bit_cast(short, __float2bfloat16(v.x));
    s.y = __builtin_bit_cast(short, __float2bfloat16(v.y));
    s.z = __builtin_bit_cast(short, __float2bfloat16(v.z));
    s.w = __builtin_bit_cast(short, __float2bfloat16(v.w));
    reinterpret_cast<short4*>(dst)[i] = s;
  } else if (bid < 508) {
    float* feat = shbuf;
    const int pb = bid - 256;        // 0..251
    const int dd = pb >> 1;          // 0..125 -> diff = dd - 62
    const int which = pb & 1;
    const float* FC = which ? fcy : fcx;
    __hip_bfloat16* OUT = which ? pemby_b : pembx_b;
    if (tid < 64) {
      const float diff = (float)(dd - 62);
      const float dm = powf(1000.f, (float)tid * (1.f / 64.f));
      const float aa = diff / dm;
      feat[tid] = sinf(aa);
      feat[tid + 64] = cosf(aa);
    }
    __syncthreads();
    const float4* row4 = reinterpret_cast<const float4*>(FC + tid * 128);
    const float4* f4 = reinterpret_cast<const float4*>(feat);
    float s0 = 0.f, s1 = 0.f, s2 = 0.f, s3 = 0.f;
#pragma unroll
    for (int f = 0; f < 32; ++f) {
      const float4 fv = f4[f];
      const float4 rv = row4[f];
      s0 = fmaf(fv.x, rv.x, s0);
      s1 = fmaf(fv.y, rv.y, s1);
      s2 = fmaf(fv.z, rv.z, s2);
      s3 = fmaf(fv.w, rv.w, s3);
    }
    const float s = ((s0 + s1) + (s2 + s3)) * 0.70710678118654752440f;
    OUT[(size_t)dd * 256 + tid] = __float2bfloat16(s);
  } else {
    float (*t)[65] = reinterpret_cast<float(*)[65]>(shbuf);
    const int b = bid - 508;
    const int p0 = (b & 63) * 64;
    const int c0 = ((b >> 6) & 3) * 64;
    const int n = b >> 8;
    {
      const int pl = tid & 63, cg = tid >> 6;
#pragma unroll
      for (int i = 0; i < 16; ++i) {
        const int cl = cg * 16 + i;
        t[cl][pl] = x[((size_t)n * 256 + c0 + cl) * PQ + p0 + pl];
      }
    }
    __syncthreads();
    const int cl = tid & 63;
#pragma unroll
    for (int j = 0; j < 16; ++j) {
      const int pl = (tid >> 6) + 4 * j;
      ((__hip_bfloat16*)xb)[((size_t)n * PQ + p0 + pl) * 256 + c0 + cl] =
          __float2bfloat16(t[cl][pl]);
    }
  }
}

// ---------------------------------------------------------------------------
// Fused Q + K/V projection GEMMs with LDS-staged swizzled B-tiles (R17-proven)
// ---------------------------------------------------------------------------
__global__ __launch_bounds__(256) void gemm_qkv_kernel(
    const __hip_bfloat16* __restrict__ xb,
    const __hip_bfloat16* __restrict__ qw, const __hip_bfloat16* __restrict__ kw,
    const __hip_bfloat16* __restrict__ vw, const float* __restrict__ ab,
    const float* __restrict__ gb, __hip_bfloat16* __restrict__ qab,
    __hip_bfloat16* __restrict__ qgb, __hip_bfloat16* __restrict__ k_lb,
    __hip_bfloat16* __restrict__ v_t) {
  __shared__ short bt[32 * 256];   // 16 KB, XOR-swizzled 16B chunks
  const int bid = blockIdx.x;
  const int tid = threadIdx.x;
  const int wv = tid >> 6, l = tid & 63, lc = l & 15, lq = l >> 4;

  const bool isQ = (bid < 1024);
  int n, o0, p0;
  bool isV = false;
  const __hip_bfloat16* W;
  if (isQ) {
    n = bid & 1;
    o0 = ((bid >> 1) & 3) * 64;
    p0 = (bid >> 3) * 32;
    W = qw;
  } else {
    const int kb2 = bid - 1024;
    n = kb2 & 1;
    o0 = ((kb2 >> 1) & 3) * 64;
    isV = ((kb2 >> 3) & 1) != 0;
    p0 = (kb2 >> 4) * 32;
    W = isV ? vw : kw;
  }

  {
    const int row = tid >> 3;            // 0..31
    const int pk = p0 + row;
    const int gp = isQ ? pk : ((pk >> 5) * 128 + (pk & 31) * 2);
    const short* src = (const short*)xb + ((size_t)n * PQ + gp) * 256;
#pragma unroll
    for (int j = 0; j < 4; ++j) {
      const int chunk = (tid & 7) + 8 * j;   // 16B chunk index 0..31
      const int4 v = *reinterpret_cast<const int4*>(src + chunk * 8);
      *reinterpret_cast<int4*>(bt + row * 256 + ((chunk ^ (row & 7)) << 3)) = v;
    }
  }
  __syncthreads();

  const short* ar =
      (const short*)W + ((size_t)(o0 + wv * 16 + lc)) * 256 + 8 * lq;
  f32x4 acc0 = {0.f, 0.f, 0.f, 0.f};
  f32x4 acc1 = {0.f, 0.f, 0.f, 0.f};
#pragma unroll
  for (int kt = 0; kt < 8; ++kt) {
    const short8 af = *reinterpret_cast<const short8*>(ar + kt * 32);
    const int c0i = lq + 4 * kt;           // chunk col for shorts 8lq+32kt
    const short8 bf0 = *reinterpret_cast<const short8*>(
        bt + lc * 256 + ((c0i ^ (lc & 7)) << 3));
    const short8 bf1 = *reinterpret_cast<const short8*>(
        bt + (16 + lc) * 256 + ((c0i ^ ((16 + lc) & 7)) << 3));
    acc0 = __builtin_amdgcn_mfma_f32_16x16x32_bf16(af, bf0, acc0, 0, 0, 0);
    acc1 = __builtin_amdgcn_mfma_f32_16x16x32_bf16(af, bf1, acc1, 0, 0, 0);
  }

  if (isQ) {
#pragma unroll
    for (int r = 0; r < 4; ++r) {
      const int o = o0 + wv * 16 + 4 * lq + r;
      const float abo = ab[o], gbo = gb[o];
      const int head = o >> 5, dd = o & 31;
      const size_t gbase = (size_t)(n * 8 + head) * PQ;
      const float a_[2] = {acc0[r], acc1[r]};
#pragma unroll
      for (int nf = 0; nf < 2; ++nf) {
        const int p = p0 + 16 * nf + lc;
        const size_t idx = (gbase + p) * 32 + dd;
        qab[idx] = __float2bfloat16(a_[nf] + abo);
        qgb[idx] = __float2bfloat16(a_[nf] + gbo);
      }
    }
  } else {
#pragma unroll
    for (int r = 0; r < 4; ++r) {
      const int o = o0 + wv * 16 + 4 * lq + r;
      const int head = o >> 5, dd = o & 31;
      const float a_[2] = {acc0[r], acc1[r]};
#pragma unroll
      for (int nf = 0; nf < 2; ++nf) {
        const int p = p0 + 16 * nf + lc;
        if (!isV) {
          k_lb[((size_t)(n * 8 + head) * PKV + p) * 32 + dd] =
              __float2bfloat16(a_[nf]);
        } else {
          v_t[((size_t)(n * 8 + head) * 32 + dd) * PKV + p] =
              __float2bfloat16(a_[nf]);
        }
      }
    }
  }
}

// ---------------------------------------------------------------------------
// EX table via MFMA (R17-proven, unchanged; bf16 output).
// ---------------------------------------------------------------------------
__global__ __launch_bounds__(256) void ex_kernel(
    const __hip_bfloat16* __restrict__ qgb_b,
    const __hip_bfloat16* __restrict__ pembx_b,
    __hip_bfloat16* __restrict__ EX) {
  const int i = blockIdx.x;       // x
  const int g = blockIdx.y;
  const int head = g & 7;
  const int wv = threadIdx.x >> 6;
  const int l = threadIdx.x & 63;
  const int lc = l & 15, lq = l >> 4;

  const int rowi = wv * 16 + lc;  // y
  const int p = rowi * 64 + i;
  const short8 a = *reinterpret_cast<const short8*>(
      (const short*)qgb_b + ((size_t)g * PQ + p) * 32 + 8 * lq);

  const int drow0 = i - 2 * lc + 62;
  const int drow1 = i - 2 * (lc + 16) + 62;
  const short8 b0 = *reinterpret_cast<const short8*>(
      (const short*)pembx_b + (size_t)drow0 * 256 + head * 32 + 8 * lq);
  const short8 b1 = *reinterpret_cast<const short8*>(
      (const short*)pembx_b + (size_t)drow1 * 256 + head * 32 + 8 * lq);

  const f32x4 zero = {0.f, 0.f, 0.f, 0.f};
  const f32x4 c0 = __builtin_amdgcn_mfma_f32_16x16x32_bf16(a, b0, zero, 0, 0, 0);
  const f32x4 c1 = __builtin_amdgcn_mfma_f32_16x16x32_bf16(a, b1, zero, 0, 0, 0);

  const int lox = max((i - 16) >> 1, 0);
  const int hix = min(((i + 17) >> 1) + 1, 32);
#pragma unroll
  for (int r = 0; r < 4; ++r) {
    const int rowr = wv * 16 + 4 * lq + r;
    const int pr = rowr * 64 + i;
    __hip_bfloat16* o = EX + ((size_t)g * PQ + pr) * EXSTRIDE;
    o[lc] = __float2bfloat16(
        (lc >= lox && lc < hix) ? (c0[r] - M0) : -1e30f);
    o[16 + lc] = __float2bfloat16(
        (lc + 16 >= lox && lc + 16 < hix) ? (c1[r] - M0) : -1e30f);
    if (lc < 4) o[32 + lc] = __float2bfloat16(-1e30f);
  }
}

// ---------------------------------------------------------------------------
// MFMA local-window attention v4-bisect: 16x x 8y tiles, 8 waves (wave = one
// y-row, FULL ky range -> no parity split, no merge). EX read from the
// R17-proven global bf16 table; EY computed in-kernel per wave (R17-proven
// formula; eybuf slice is wave-private). Main loop and fused att2b epilogue
// are the R17-proven bodies with per-wave indexing.
// ---------------------------------------------------------------------------
__global__ __launch_bounds__(512, 8) void attn_mfma_kernel(
    const __hip_bfloat16* __restrict__ qab_b,
    const __hip_bfloat16* __restrict__ qgb_b,
    const __hip_bfloat16* __restrict__ k_lb,
    const __hip_bfloat16* __restrict__ v_t,
    const __hip_bfloat16* __restrict__ EX,
    const __hip_bfloat16* __restrict__ pemby_b,
    __hip_bfloat16* __restrict__ attb) {
  const int g = blockIdx.y;    // n*8 + head
  const int nImg = g >> 3, hd = g & 7;
  const int tile = blockIdx.x;     // 0..31
  const int tx = (tile & 3) * 16;
  const int ty = (tile >> 2) * 8;
  const int w = threadIdx.x >> 6;  // 0..7: y-row wave
  const int y = ty + w;
  const int l = threadIdx.x & 63;
  const int lc = l & 15;   // col lane (q for S^T / vd for O)
  const int lq = l >> 4;   // quarter

  __shared__ float eybuf[8][EYSTRIDE][16];  // [yrow][t][q]  (wave-private)
  __shared__ float obuf[8][16][33];         // [yrow][q][vd]  (wave-private)

  const int KLO = max((tx - 16) >> 1, 0);
  const int lo_y = max((y - 16) >> 1, 0);
  const int hi_y = min(((y + 17) >> 1) + 1, 32);
  const int NKY = hi_y - lo_y;

  const int xq = tx + lc;
  const int pq_ = y * 64 + xq;

  // Qa B-frag: lane holds Qa[d=8lq+j][q=lc]
  const short8 qa = *reinterpret_cast<const short8*>(
      (const short*)qab_b + ((size_t)g * PQ + pq_) * 32 + 8 * lq);

  // per-lane loop-invariant ex registers (mask, M0, x-term baked; bf16 table)
  const short* exr = (const short*)EX + ((size_t)g * PQ + pq_) * EXSTRIDE;
  float exC0[4], exC1[4];
#pragma unroll
  for (int r = 0; r < 4; ++r) {
    exC0[r] = __bfloat162float(
        __builtin_bit_cast(__hip_bfloat16, exr[KLO + 4 * lq + r]));
    exC1[r] = __bfloat162float(
        __builtin_bit_cast(__hip_bfloat16, exr[min(KLO + 16 + 4 * lq + r, 35)]));
  }

  // EY computed in-kernel by EVERY wave for its own y-row (R17-proven formula)
  {
    const short8 ag = *reinterpret_cast<const short8*>(
        (const short*)qgb_b + ((size_t)g * PQ + pq_) * 32 + 8 * lq);
    const int dr0 = y - 2 * (lo_y + lc) + 62;
    const int dr1 = y - 2 * (lo_y + lc + 16) + 62;
    const short8 pb0 = *reinterpret_cast<const short8*>(
        (const short*)pemby_b + (size_t)dr0 * 256 + hd * 32 + 8 * lq);
    const short8 pb1 = *reinterpret_cast<const short8*>(
        (const short*)pemby_b + (size_t)dr1 * 256 + hd * 32 + 8 * lq);
    const f32x4 zero = {0.f, 0.f, 0.f, 0.f};
    const f32x4 e0 = __builtin_amdgcn_mfma_f32_16x16x32_bf16(ag, pb0, zero, 0, 0, 0);
    const f32x4 e1 = __builtin_amdgcn_mfma_f32_16x16x32_bf16(ag, pb1, zero, 0, 0, 0);
#pragma unroll
    for (int r = 0; r < 4; ++r) eybuf[w][lc][4 * lq + r] = e0[r];
    if (lc < 4) {
#pragma unroll
      for (int r = 0; r < 4; ++r) eybuf[w][16 + lc][4 * lq + r] = e1[r];
    }
  }
  __syncthreads();   // belt-and-braces (eybuf/obuf slices are wave-private)

  const __hip_bfloat16* kb =
      k_lb + ((size_t)g * PKV + (size_t)lo_y * 32) * 32;
  const __hip_bfloat16* kb0 = kb + (KLO + lc) * 32 + 8 * lq;
  const __hip_bfloat16* kb1 = kb + min(KLO + 16 + lc, 31) * 32 + 8 * lq;
  const __hip_bfloat16* vb0 =
      v_t + ((size_t)g * 32 + lc) * PKV + (size_t)lo_y * 32 + KLO + 8 * lq;
  const __hip_bfloat16* vb1 = vb0 + 16 * PKV;

  f32x4 acc0 = {0.f, 0.f, 0.f, 0.f};
  f32x4 acc1 = {0.f, 0.f, 0.f, 0.f};
  float lp = 0.f;
  const int srcA = lc + ((l & 16) << 1);  // lane lc + 32*(lq&1)
  const int srcB = srcA + 16;
  const bool hiL = (l & 32) != 0;

#pragma unroll 1
  for (int t = 0; t < NKY; ++t) {
    const short8 k0 = *reinterpret_cast<const short8*>(kb0 + t * 1024);
    const short8 k1 = *reinterpret_cast<const short8*>(kb1 + t * 1024);
    const short8 v0 = *reinterpret_cast<const short8*>(vb0 + t * 32);
    const short8 v1 = *reinterpret_cast<const short8*>(vb1 + t * 32);
    const f32x4 zero = {0.f, 0.f, 0.f, 0.f};
    // S^T tiles: rows kx_local = 4*lq + r, cols q = lc
    const f32x4 s0 = __builtin_amdgcn_mfma_f32_16x16x32_bf16(k0, qa, zero, 0, 0, 0);
    const f32x4 s1 = __builtin_amdgcn_mfma_f32_16x16x32_bf16(k1, qa, zero, 0, 0, 0);
    const float eyC = eybuf[w][t][lc];
    float p0[4], p1[4];
#pragma unroll
    for (int r = 0; r < 4; ++r) {
      p0[r] = __expf(s0[r] + exC0[r] + eyC);   // masked: exC=-1e30 -> 0
      p1[r] = __expf(s1[r] + exC1[r] + eyC);
    }
    lp += ((p0[0] + p0[1]) + (p0[2] + p0[3])) +
          ((p1[0] + p1[1]) + (p1[2] + p1[3]));
    int w00, w01, w10, w11;
    asm("v_cvt_pk_bf16_f32 %0, %1, %2" : "=v"(w00) : "v"(p0[0]), "v"(p0[1]));
    asm("v_cvt_pk_bf16_f32 %0, %1, %2" : "=v"(w01) : "v"(p0[2]), "v"(p0[3]));
    asm("v_cvt_pk_bf16_f32 %0, %1, %2" : "=v"(w10) : "v"(p1[0]), "v"(p1[1]));
    asm("v_cvt_pk_bf16_f32 %0, %1, %2" : "=v"(w11) : "v"(p1[2]), "v"(p1[3]));
    const int a0 = __shfl(w00, srcA, 64), b0 = __shfl(w10, srcA, 64);
    const int a1 = __shfl(w01, srcA, 64), b1 = __shfl(w11, srcA, 64);
    const int a2 = __shfl(w00, srcB, 64), b2 = __shfl(w10, srcB, 64);
    const int a3 = __shfl(w01, srcB, 64), b3 = __shfl(w11, srcB, 64);
    int4 pw;
    pw.x = hiL ? b0 : a0;
    pw.y = hiL ? b1 : a1;
    pw.z = hiL ? b2 : a2;
    pw.w = hiL ? b3 : a3;
    const short8 pf = __builtin_bit_cast(short8, pw);
    acc0 = __builtin_amdgcn_mfma_f32_16x16x32_bf16(pf, v0, acc0, 0, 0, 0);
    acc1 = __builtin_amdgcn_mfma_f32_16x16x32_bf16(pf, v1, acc1, 0, 0, 0);
  }

  // l: sum over the 4 lq groups -> every lane holds L[q=lc]
  lp += __shfl_xor(lp, 16);
  lp += __shfl_xor(lp, 32);
  const float invall = 1.f / lp;

  // fused att2b epilogue: O*inv -> obuf (wave-private slice) -> bf16 attb
#pragma unroll
  for (int r = 0; r < 4; ++r) {
    const float inv = __shfl(invall, 4 * lq + r, 16);  // L for q = 4lq+r
    obuf[w][4 * lq + r][lc] = acc0[r] * inv;
    obuf[w][4 * lq + r][16 + lc] = acc1[r] * inv;
  }
  const int qp = l >> 2;
  const int ch = (l & 3) * 8;
  short8 sv;
#pragma unroll
  for (int j = 0; j < 8; ++j)
    sv[j] = __builtin_bit_cast(short, __float2bfloat16(obuf[w][qp][ch + j]));
  const int p = y * 64 + tx + qp;
  *reinterpret_cast<short8*>(
      (short*)attb + ((size_t)nImg * PQ + p) * 256 + hd * 32 + ch) = sv;
}

// ---------------------------------------------------------------------------
// MFMA GEMM: output projection + bias + gamma + residual (R17-proven).
// ---------------------------------------------------------------------------
__global__ __launch_bounds__(256) void gemm_out_kernel(
    const __hip_bfloat16* __restrict__ attb,
    const __hip_bfloat16* __restrict__ pw, const float* __restrict__ pb,
    const float* __restrict__ gamma, const float* __restrict__ x_in,
    float* __restrict__ out) {
  __shared__ short bt[32 * 256];   // 16 KB
  const int p0 = blockIdx.x * 32;
  const int o0 = blockIdx.y * 64;
  const int n = blockIdx.z;
  const int tid = threadIdx.x;
  const int wv = tid >> 6, l = tid & 63, lc = l & 15, lq = l >> 4;

  {
    const int row = tid >> 3;
    const short* src = (const short*)attb + ((size_t)n * PQ + p0 + row) * 256;
#pragma unroll
    for (int j = 0; j < 4; ++j) {
      const int chunk = (tid & 7) + 8 * j;
      const int4 v = *reinterpret_cast<const int4*>(src + chunk * 8);
      *reinterpret_cast<int4*>(bt + row * 256 + ((chunk ^ (row & 7)) << 3)) = v;
    }
  }
  __syncthreads();

  const short* ar =
      (const short*)pw + ((size_t)(o0 + wv * 16 + lc)) * 256 + 8 * lq;
  f32x4 acc0 = {0.f, 0.f, 0.f, 0.f};
  f32x4 acc1 = {0.f, 0.f, 0.f, 0.f};
#pragma unroll
  for (int kt = 0; kt < 8; ++kt) {
    const short8 af = *reinterpret_cast<const short8*>(ar + kt * 32);
    const int c0i = lq + 4 * kt;
    const short8 bf0 = *reinterpret_cast<const short8*>(
        bt + lc * 256 + ((c0i ^ (lc & 7)) << 3));
    const short8 bf1 = *reinterpret_cast<const short8*>(
        bt + (16 + lc) * 256 + ((c0i ^ ((16 + lc) & 7)) << 3));
    acc0 = __builtin_amdgcn_mfma_f32_16x16x32_bf16(af, bf0, acc0, 0, 0, 0);
    acc1 = __builtin_amdgcn_mfma_f32_16x16x32_bf16(af, bf1, acc1, 0, 0, 0);
  }
  const float gm = gamma[0];
#pragma unroll
  for (int r = 0; r < 4; ++r) {
    const int o = o0 + wv * 16 + 4 * lq + r;   // C row = 4*lq + r
    const float bo = pb[o];
    const size_t obase = ((size_t)n * 256 + o) * PQ;
    const size_t i0 = obase + (p0 + 0 + lc);
    const size_t i1 = obase + (p0 + 16 + lc);
    out[i0] = fmaf(gm, acc0[r] + bo, x_in[i0]);
    out[i1] = fmaf(gm, acc1[r] + bo, x_in[i1]);
  }
}

// ---------------------------------------------------------------------------
extern "C" void kernel_launch(void* const* d_in, const int* in_sizes, int n_in,
                              void* d_out, int out_size, void* d_ws,
                              size_t ws_size, hipStream_t stream) {
  const float* x = (const float*)d_in[0];
  const float* q_w = (const float*)d_in[1];
  const float* k_w = (const float*)d_in[2];
  const float* v_w = (const float*)d_in[3];
  const float* fcx_w = (const float*)d_in[4];
  const float* fcy_w = (const float*)d_in[5];
  const float* ab = (const float*)d_in[6];
  const float* gb = (const float*)d_in[7];
  const float* proj_w = (const float*)d_in[8];
  const float* proj_b = (const float*)d_in[9];
  const float* gamma = (const float*)d_in[10];
  float* out = (float*)d_out;

  __hip_bfloat16* bp = (__hip_bfloat16*)d_ws;
  __hip_bfloat16* EX = bp;      bp += 2359296;   // 16*4096*36 bf16
  __hip_bfloat16* qab_b = bp;   bp += 2097152;
  __hip_bfloat16* qgb_b = bp;   bp += 2097152;
  __hip_bfloat16* k_lb = bp;    bp += 524288;
  __hip_bfloat16* v_t = bp;     bp += 524288;
  __hip_bfloat16* pembx_b = bp; bp += 32256;
  __hip_bfloat16* pemby_b = bp; bp += 32256;
  __hip_bfloat16* qw_b = bp;    bp += 65536;
  __hip_bfloat16* kw_b = bp;    bp += 65536;
  __hip_bfloat16* vw_b = bp;    bp += 65536;
  __hip_bfloat16* pw_b = bp;    bp += 65536;
  __hip_bfloat16* xb = bp;      bp += 2097152;
  __hip_bfloat16* attb = bp;    bp += 2097152;
  // total = 12,123,136 bf16 = 24.2 MB

  prep_kernel<<<dim3(1020), 256, 0, stream>>>(q_w, k_w, v_w, proj_w, qw_b,
                                              kw_b, vw_b, pw_b, fcx_w, fcy_w,
                                              pembx_b, pemby_b, x, xb);
  gemm_qkv_kernel<<<dim3(1536), 256, 0, stream>>>(xb, qw_b, kw_b, vw_b, ab,
                                                  gb, qab_b, qgb_b, k_lb, v_t);
  ex_kernel<<<dim3(64, 16), 256, 0, stream>>>(qgb_b, pembx_b, EX);
  attn_mfma_kernel<<<dim3(32, 16), 512, 0, stream>>>(qab_b, qgb_b, k_lb, v_t,
                                                     EX, pemby_b, attb);
  gemm_out_kernel<<<dim3(128, 4, 2), 256, 0, stream>>>(attb, pw_b, proj_b,
                                                       gamma, x, out);
}